// Round 6
// baseline (492.454 us; speedup 1.0000x reference)
//
#include <hip/hip_runtime.h>

// ---------------------------------------------------------------------------
// LightningAttention2: bitlinear QKV -> RoPE -> chunked (softmax intra +
// linear inter) attention -> rms_norm -> bitlinear proj.
//
// Shapes: B=2, N=8192, DIM=1024, H=16, Dh=64, CHUNK=128, T=64. M = B*N = 16384.
//
// Numerics: activation quant -> integers in [-128,127]; weight quant ->
// {-1,0,1}. Both exact in bf16 => bf16 MFMA with fp32 accumulate is an EXACT
// integer GEMM. Dequant scales in fp32 epilogue. Attention fp32 softmax.
//
// Determinism: NO float atomics. Fixed-order two-stage |w| reduction.
//
// R12 = R11 (passing, absmax 0.02539062) + k_rope ELIMINATED by fusing RoPE
// into the QKV GEMM *epilogue* (NOT the cursed attention-load fusion of
// R4/R5/R10 — attention kernels are R11-byte-identical). In the OUT_BF16
// epilogue: pairs (2i,2i+1) are adjacent lanes, partner via __shfl_xor(v,1);
// wave-uniform part check selects q/k strips only; rope applied to the fp32
// value BEFORE the single bf16 round (slightly more accurate than the old
// rope(bf16)->bf16 round-trip; absmax expected ~0.025, threshold 0.0466).
// Saves ~200 MB of qkv RW (~35-40us).
// GEMM core: R11 4-phase structure unchanged (proven value-identical).
// ---------------------------------------------------------------------------

typedef unsigned short USH;
typedef __attribute__((ext_vector_type(8))) short short8;
typedef __attribute__((ext_vector_type(4))) float f32x4;
typedef __attribute__((ext_vector_type(4))) USH us4;

__device__ __forceinline__ float b2f(USH u) { return __uint_as_float(((unsigned)u) << 16); }
__device__ __forceinline__ USH f2b(float f) {
    unsigned u = __float_as_uint(f);
    u += 0x7fffu + ((u >> 16) & 1u);   // round-to-nearest-even
    return (USH)(u >> 16);
}
__device__ __forceinline__ f32x4 mfma16(short8 a, short8 b, f32x4 c) {
    return __builtin_amdgcn_mfma_f32_16x16x32_bf16(a, b, c, 0, 0, 0);
}
// async global->LDS, 16B per lane; LDS dest = wave-uniform base + lane*16
__device__ __forceinline__ void gload_lds16(const void* g, void* l) {
    __builtin_amdgcn_global_load_lds(
        (const __attribute__((address_space(1))) unsigned*)g,
        (__attribute__((address_space(3))) unsigned*)l, 16, 0, 0);
}

// block reductions over 256 threads (4 waves)
__device__ __forceinline__ float blk_sum(float v, float* red) {
#pragma unroll
    for (int o = 32; o; o >>= 1) v += __shfl_xor(v, o);
    __syncthreads();
    if ((threadIdx.x & 63) == 0) red[threadIdx.x >> 6] = v;
    __syncthreads();
    return red[0] + red[1] + red[2] + red[3];
}
__device__ __forceinline__ float blk_max(float v, float* red) {
#pragma unroll
    for (int o = 32; o; o >>= 1) v = fmaxf(v, __shfl_xor(v, o));
    __syncthreads();
    if ((threadIdx.x & 63) == 0) red[threadIdx.x >> 6] = v;
    __syncthreads();
    return fmaxf(fmaxf(red[0], red[1]), fmaxf(red[2], red[3]));
}

// ---------------------------------------------------------------------------
// K1a: per-block partial sums of |w| (deterministic — no atomics)
__global__ __launch_bounds__(256) void k_wabs(const float* __restrict__ qw,
                                              const float* __restrict__ pw,
                                              float* __restrict__ partials) {
    __shared__ float red[4];
    int which = blockIdx.y;
    const float4* p = (const float4*)(which ? pw : qw);
    int n4 = which ? (1024 * 1024 / 4) : (3072 * 1024 / 4);
    float s = 0.f;
    for (int i = blockIdx.x * 256 + threadIdx.x; i < n4; i += 256 * 256) {
        float4 v = p[i];
        s += fabsf(v.x) + fabsf(v.y) + fabsf(v.z) + fabsf(v.w);
    }
#pragma unroll
    for (int o = 32; o; o >>= 1) s += __shfl_xor(s, o);
    if ((threadIdx.x & 63) == 0) red[threadIdx.x >> 6] = s;
    __syncthreads();
    if (threadIdx.x == 0)
        partials[which * 256 + blockIdx.x] = red[0] + red[1] + red[2] + red[3];
}

// K1b: fixed-order reduction of 256 partials per matrix (deterministic)
__global__ __launch_bounds__(256) void k_wsum(const float* __restrict__ partials,
                                              float* __restrict__ sums) {
    __shared__ double red[4];
    int which = blockIdx.x;
    double v = (double)partials[which * 256 + threadIdx.x];
#pragma unroll
    for (int o = 32; o; o >>= 1) v += __shfl_xor(v, o);
    if ((threadIdx.x & 63) == 0) red[threadIdx.x >> 6] = v;
    __syncthreads();
    if (threadIdx.x == 0)
        sums[which] = (float)(red[0] + red[1] + red[2] + red[3]);
}

// ---------------------------------------------------------------------------
// K2: ternary-quantize both weight matrices to bf16 {-1,0,1}
__global__ __launch_bounds__(256) void k_wquant(const float* __restrict__ qw,
                                                const float* __restrict__ pw,
                                                const float* __restrict__ sums,
                                                USH* __restrict__ wqk, USH* __restrict__ wqp) {
    int id = blockIdx.x * 256 + threadIdx.x;   // 0 .. 1048575 (float4 units)
    float4 v; USH* dst; float sc;
    if (id < 786432) {
        v = ((const float4*)qw)[id];
        sc = 1.f / fmaxf(sums[0] * (1.f / 3145728.f), 1e-5f);
        dst = wqk + (size_t)id * 4;
    } else {
        int j = id - 786432;
        v = ((const float4*)pw)[j];
        sc = 1.f / fmaxf(sums[1] * (1.f / 1048576.f), 1e-5f);
        dst = wqp + (size_t)j * 4;
    }
    us4 o;
    o.x = f2b(fminf(fmaxf(rintf(v.x * sc), -1.f), 1.f));
    o.y = f2b(fminf(fmaxf(rintf(v.y * sc), -1.f), 1.f));
    o.z = f2b(fminf(fmaxf(rintf(v.z * sc), -1.f), 1.f));
    o.w = f2b(fminf(fmaxf(rintf(v.w * sc), -1.f), 1.f));
    *(us4*)dst = o;
}

// ---------------------------------------------------------------------------
// K3: RMS(eps_bit) * nw -> per-row int8 quant -> bf16 integers + inv_a
__global__ __launch_bounds__(256) void k_actq(const float* __restrict__ x,
                                              const float* __restrict__ nw,
                                              USH* __restrict__ xq, float* __restrict__ inva) {
    __shared__ float red[4];
    int row = blockIdx.x, tid = threadIdx.x;
    float4 v = ((const float4*)(x + (size_t)row * 1024))[tid];
    float4 w = ((const float4*)nw)[tid];
    float ss = v.x * v.x + v.y * v.y + v.z * v.z + v.w * v.w;
    ss = blk_sum(ss, red);
    float r1 = rsqrtf(ss * (1.f / 1024.f) + 1.1920929e-07f);
    float x0 = v.x * r1 * w.x, x1 = v.y * r1 * w.y, x2 = v.z * r1 * w.z, x3 = v.w * r1 * w.w;
    float am = fmaxf(fmaxf(fabsf(x0), fabsf(x1)), fmaxf(fabsf(x2), fabsf(x3)));
    am = blk_max(am, red);
    float amc = fmaxf(am, 1e-5f);
    float sc = 127.f / amc;
    us4 o;
    o.x = f2b(fminf(fmaxf(rintf(x0 * sc), -128.f), 127.f));
    o.y = f2b(fminf(fmaxf(rintf(x1 * sc), -128.f), 127.f));
    o.z = f2b(fminf(fmaxf(rintf(x2 * sc), -128.f), 127.f));
    o.w = f2b(fminf(fmaxf(rintf(x3 * sc), -128.f), 127.f));
    *(us4*)(xq + (size_t)row * 1024 + tid * 4) = o;
    if (tid == 0) inva[row] = amc * (1.f / 127.f);
}

// ---------------------------------------------------------------------------
// K9: rms_norm(out, norm_w) then bitlinear's own RMS(eps_bit)*proj_nw + quant
__global__ __launch_bounds__(256) void k_norm2q(const USH* __restrict__ oat,
                                                const float* __restrict__ nw,
                                                const float* __restrict__ pnw,
                                                USH* __restrict__ xq, float* __restrict__ inva) {
    __shared__ float red[4];
    int row = blockIdx.x, tid = threadIdx.x;
    us4 ov = *(const us4*)(oat + (size_t)row * 1024 + tid * 4);
    float o0 = b2f(ov.x), o1 = b2f(ov.y), o2 = b2f(ov.z), o3 = b2f(ov.w);
    float4 w = ((const float4*)nw)[tid];
    float4 pw = ((const float4*)pnw)[tid];
    float ss1 = blk_sum(o0 * o0 + o1 * o1 + o2 * o2 + o3 * o3, red);
    float r1 = rsqrtf(ss1 * (1.f / 1024.f) + 1e-6f);
    float y0 = o0 * r1 * w.x, y1 = o1 * r1 * w.y, y2 = o2 * r1 * w.z, y3 = o3 * r1 * w.w;
    float ss2 = blk_sum(y0 * y0 + y1 * y1 + y2 * y2 + y3 * y3, red);
    float r2 = rsqrtf(ss2 * (1.f / 1024.f) + 1.1920929e-07f);
    float z0 = y0 * r2 * pw.x, z1 = y1 * r2 * pw.y, z2 = y2 * r2 * pw.z, z3 = y3 * r2 * pw.w;
    float am = fmaxf(fmaxf(fabsf(z0), fabsf(z1)), fmaxf(fabsf(z2), fabsf(z3)));
    am = blk_max(am, red);
    float amc = fmaxf(am, 1e-5f);
    float sc = 127.f / amc;
    us4 q;
    q.x = f2b(fminf(fmaxf(rintf(z0 * sc), -128.f), 127.f));
    q.y = f2b(fminf(fmaxf(rintf(z1 * sc), -128.f), 127.f));
    q.z = f2b(fminf(fmaxf(rintf(z2 * sc), -128.f), 127.f));
    q.w = f2b(fminf(fmaxf(rintf(z3 * sc), -128.f), 127.f));
    *(us4*)(xq + (size_t)row * 1024 + tid * 4) = q;
    if (tid == 0) inva[row] = amc * (1.f / 127.f);
}

// ---------------------------------------------------------------------------
// GEMM R12: out[m][n] = (sum_k A[m][k]*W[n][k]) * inv_a[m] * wscale + bias[n]
// A: [M][K] bf16 ints; W: [N][K] bf16 ternary. K = 1024 (both calls).
// Core identical to R11 (proven value-identical; absmax canary held).
// OUT_BF16 epilogue additionally applies RoPE to the q,k column strips:
// partner element via __shfl_xor(v,1) (pairs are adjacent lanes), cos/sin
// from the 1 MB L2-resident tables, wave-uniform part check (each wave's
// 64-col strip lies entirely in q, k, or v).
template <bool OUT_BF16>
__global__ __launch_bounds__(512, 2) void k_gemm(const USH* __restrict__ A, const USH* __restrict__ W,
                                                 const float* __restrict__ inva,
                                                 const float* __restrict__ wsum, float wcnt,
                                                 const float* __restrict__ bias,
                                                 const float* __restrict__ cs,
                                                 const float* __restrict__ sn,
                                                 void* __restrict__ out, int Nn, int K) {
    __shared__ __align__(16) USH lds[3 * 16384];   // per buf: A @ +0, B @ +8192 (USH units)
    const int tid = threadIdx.x;
    const int wv = tid >> 6, lane = tid & 63, quad = lane >> 4, lid = lane & 15;
    const int wr = wv >> 2, wc = wv & 3;

    // bijective XCD-aware swizzle (grids are 768 / 256 blocks: both %8 == 0)
    const int nbn = gridDim.x;
    const int nwg = nbn * gridDim.y;
    const int bid = blockIdx.y * nbn + blockIdx.x;
    const int swb = (bid & 7) * (nwg >> 3) + (bid >> 3);
    const int bn = swb % nbn, bm = swb / nbn;

    const int T = K >> 5;   // K-steps of 32 (T = 32)

    // staging source pointers (pre-swizzled): wave wv, round j stages LDS rows
    // (j*8+wv)*16 .. +15; lane: row = base + (l>>2), slot = l&3,
    // source 16B-slot = slot ^ swz(row)
    const USH* ag[2]; const USH* wg[2];
#pragma unroll
    for (int j = 0; j < 2; j++) {
        int r = (j * 8 + wv) * 16 + (lane >> 2);
        int sw = (r & 3) ^ ((r >> 2) & 1);
        int c16 = (lane & 3) ^ sw;
        ag[j] = A + (size_t)(bm * 256 + r) * K + c16 * 8;
        wg[j] = W + (size_t)(bn * 256 + r) * K + c16 * 8;
    }
    // read-side swizzled slot: frag row = (multiple of 16) + lid, so
    // swz(row) == (lid&3)^((lid>>2)&1) for every fragment => per-lane const.
    const int sq = quad ^ ((lid & 3) ^ ((lid >> 2) & 1));
    const int arow = (wr * 128 + lid) * 32 + sq * 8;   // + mt*16*32
    const int brow = (wc * 64 + lid) * 32 + sq * 8;    // + nt*16*32

    f32x4 acc[8][4];
#pragma unroll
    for (int mt = 0; mt < 8; mt++)
#pragma unroll
        for (int nt = 0; nt < 4; nt++)
#pragma unroll
            for (int r = 0; r < 4; r++) acc[mt][nt][r] = 0.f;

    // prologue: stage tiles 0 and 1 (per wave: 4 loads each, oldest-first)
#pragma unroll
    for (int t = 0; t < 2; t++) {
        USH* dst = &lds[t * 16384];
#pragma unroll
        for (int j = 0; j < 2; j++) {
            gload_lds16(ag[j] + t * 32, &dst[(j * 8 + wv) * 512]);
            gload_lds16(wg[j] + t * 32, &dst[8192 + (j * 8 + wv) * 512]);
        }
    }

    for (int t = 0; t < T; ++t) {
        const USH* As = &lds[(t % 3) * 16384];
        const USH* Bs = As + 8192;
        USH* Pd = &lds[((t + 2) % 3) * 16384];
        const bool pf = (t + 2 < T);
        short8 af[8], bf[4];
        if (t + 1 < T) asm volatile("s_waitcnt vmcnt(4) lgkmcnt(0)" ::: "memory");
        else           asm volatile("s_waitcnt vmcnt(0) lgkmcnt(0)" ::: "memory");
        __builtin_amdgcn_s_barrier();
        __builtin_amdgcn_sched_barrier(0);
        // -------- phase 0: af0-3, bf0-1 -> quadrant (mt0-3, nt0-1)
#pragma unroll
        for (int mt = 0; mt < 4; mt++)
            af[mt] = *(const short8*)&As[arow + mt * 512];
        bf[0] = *(const short8*)&Bs[brow + 0 * 512];
        bf[1] = *(const short8*)&Bs[brow + 1 * 512];
        if (pf) gload_lds16(ag[0] + (t + 2) * 32, &Pd[(0 * 8 + wv) * 512]);
        __builtin_amdgcn_s_barrier();
        asm volatile("s_waitcnt lgkmcnt(0)" ::: "memory");
        __builtin_amdgcn_sched_barrier(0);
        __builtin_amdgcn_s_setprio(1);
#pragma unroll
        for (int mt = 0; mt < 4; mt++)
#pragma unroll
            for (int nt = 0; nt < 2; nt++) acc[mt][nt] = mfma16(af[mt], bf[nt], acc[mt][nt]);
        __builtin_amdgcn_s_setprio(0);
        // -------- phase 1: bf2-3 -> quadrant (mt0-3, nt2-3)
        bf[2] = *(const short8*)&Bs[brow + 2 * 512];
        bf[3] = *(const short8*)&Bs[brow + 3 * 512];
        if (pf) gload_lds16(ag[1] + (t + 2) * 32, &Pd[(1 * 8 + wv) * 512]);
        __builtin_amdgcn_s_barrier();
        asm volatile("s_waitcnt lgkmcnt(0)" ::: "memory");
        __builtin_amdgcn_sched_barrier(0);
        __builtin_amdgcn_s_setprio(1);
#pragma unroll
        for (int mt = 0; mt < 4; mt++)
#pragma unroll
            for (int nt = 2; nt < 4; nt++) acc[mt][nt] = mfma16(af[mt], bf[nt], acc[mt][nt]);
        __builtin_amdgcn_s_setprio(0);
        // -------- phase 2: af4-7 -> quadrant (mt4-7, nt0-1)
#pragma unroll
        for (int mt = 4; mt < 8; mt++)
            af[mt] = *(const short8*)&As[arow + mt * 512];
        if (pf) gload_lds16(wg[0] + (t + 2) * 32, &Pd[8192 + (0 * 8 + wv) * 512]);
        __builtin_amdgcn_s_barrier();
        asm volatile("s_waitcnt lgkmcnt(0)" ::: "memory");
        __builtin_amdgcn_sched_barrier(0);
        __builtin_amdgcn_s_setprio(1);
#pragma unroll
        for (int mt = 4; mt < 8; mt++)
#pragma unroll
            for (int nt = 0; nt < 2; nt++) acc[mt][nt] = mfma16(af[mt], bf[nt], acc[mt][nt]);
        __builtin_amdgcn_s_setprio(0);
        // -------- phase 3: no reads -> quadrant (mt4-7, nt2-3)
        if (pf) gload_lds16(wg[1] + (t + 2) * 32, &Pd[8192 + (1 * 8 + wv) * 512]);
        __builtin_amdgcn_s_barrier();
        __builtin_amdgcn_sched_barrier(0);
        __builtin_amdgcn_s_setprio(1);
#pragma unroll
        for (int mt = 4; mt < 8; mt++)
#pragma unroll
            for (int nt = 2; nt < 4; nt++) acc[mt][nt] = mfma16(af[mt], bf[nt], acc[mt][nt]);
        __builtin_amdgcn_s_setprio(0);
    }

    float wm = fmaxf(wsum[0] * (1.f / wcnt), 1e-5f);
    // RoPE applies only to q,k strips (columns < 2048 of the 3072-wide qkv).
    // Each wave's 64-wide column strip lies in exactly one part => uniform.
    const bool do_rope = OUT_BF16 && (((bn * 256 + wc * 64) >> 10) < 2);
#pragma unroll
    for (int mt = 0; mt < 8; mt++)
#pragma unroll
        for (int r = 0; r < 4; r++) {
            int rowg = bm * 256 + wr * 128 + mt * 16 + quad * 4 + r;
            float ia = inva[rowg] * wm;
            int n = rowg & 8191;
#pragma unroll
            for (int nt = 0; nt < 4; nt++) {
                int colg = bn * 256 + wc * 64 + nt * 16 + lid;
                float v = acc[mt][nt][r] * ia + bias[colg];
                if (OUT_BF16) {
                    if (do_rope) {
                        float vp = __shfl_xor(v, 1);   // partner of the pair
                        int i = (nt * 16 + lid) >> 1;  // pair index in head
                        float cc = cs[n * 32 + i];
                        float ss = sn[n * 32 + i];
                        v = (lid & 1) ? (v * cc + vp * ss)    // y1 = x1*c + x0*s
                                      : (v * cc - vp * ss);   // y0 = x0*c - x1*s
                    }
                    ((USH*)out)[(size_t)rowg * Nn + colg] = f2b(v);
                } else {
                    ((float*)out)[(size_t)rowg * Nn + colg] = v;
                }
            }
        }
}

// ---------------------------------------------------------------------------
// K6: per (b,h,t) intra-chunk: S=q k^T*scale, causal softmax, O^T = V^T P^T.
// Writes o_intra (bf16) to out_attn.  LDS: 54272 B.  (qkv already roped.)
__global__ __launch_bounds__(256) void k_attn_intra(const USH* __restrict__ qkv,
                                                    USH* __restrict__ oat) {
    __shared__ char smem[36864 + 17408];
    USH* qs = (USH*)smem;                 // [seq][d]  stride 72
    USH* kqs = qs + 128 * 72;             // [seq][d]  stride 72
    USH* Ps = (USH*)smem;                 // overlay: P [seqq][seqk] stride 136
    USH* vt = (USH*)(smem + 36864);       // V^T [d][seq] stride 136
    int tid = threadIdx.x, wv = tid >> 6, lane = tid & 63, quad = lane >> 4, lid = lane & 15;
    int t = blockIdx.x, bh = blockIdx.y, b = bh >> 4, h = bh & 15;
    size_t base = ((size_t)(b * 8192 + t * 128)) * 3072 + h * 64;
    int r0 = tid >> 3, c0 = (tid & 7) * 8;
#pragma unroll
    for (int i = 0; i < 4; i++) {
        int r = i * 32 + r0;
        short8 qv = *(const short8*)(qkv + base + (size_t)r * 3072 + c0);
        short8 kv = *(const short8*)(qkv + base + (size_t)r * 3072 + 1024 + c0);
        short8 vv = *(const short8*)(qkv + base + (size_t)r * 3072 + 2048 + c0);
        *(short8*)&qs[r * 72 + c0] = qv;
        *(short8*)&kqs[r * 72 + c0] = kv;
        USH tmp[8]; *(short8*)tmp = vv;
#pragma unroll
        for (int j = 0; j < 8; j++) vt[(c0 + j) * 136 + r] = tmp[j];
    }
    __syncthreads();

    f32x4 accs[2][8];
#pragma unroll
    for (int mt = 0; mt < 2; mt++)
#pragma unroll
        for (int nt = 0; nt < 8; nt++)
#pragma unroll
            for (int r = 0; r < 4; r++) accs[mt][nt][r] = 0.f;
    int R = wv * 32;
#pragma unroll
    for (int ksx = 0; ksx < 2; ksx++) {
        int co = ksx * 32 + quad * 8;
        short8 af0 = *(const short8*)&qs[(R + lid) * 72 + co];
        short8 af1 = *(const short8*)&qs[(R + 16 + lid) * 72 + co];
        short8 bf[8];
#pragma unroll
        for (int nt = 0; nt < 8; nt++) bf[nt] = *(const short8*)&kqs[(nt * 16 + lid) * 72 + co];
#pragma unroll
        for (int nt = 0; nt < 8; nt++) {
            accs[0][nt] = mfma16(af0, bf[nt], accs[0][nt]);
            accs[1][nt] = mfma16(af1, bf[nt], accs[1][nt]);
        }
    }
    // softmax (rows owned within wave; reduce across 16 lanes of each quad)
#pragma unroll
    for (int mt = 0; mt < 2; mt++)
#pragma unroll
        for (int r = 0; r < 4; r++) {
            int row = R + mt * 16 + quad * 4 + r;
            float sv[8];
            float mx = -3.0e38f;
#pragma unroll
            for (int nt = 0; nt < 8; nt++) {
                int col = nt * 16 + lid;
                float v = accs[mt][nt][r] * 0.125f;
                sv[nt] = (col <= row) ? v : -3.0e38f;
                mx = fmaxf(mx, sv[nt]);
            }
#pragma unroll
            for (int o = 8; o; o >>= 1) mx = fmaxf(mx, __shfl_xor(mx, o));
            float sm = 0.f;
#pragma unroll
            for (int nt = 0; nt < 8; nt++) {
                float e = (sv[nt] > -1.0e38f) ? __expf(sv[nt] - mx) : 0.f;
                sv[nt] = e; sm += e;
            }
#pragma unroll
            for (int o = 8; o; o >>= 1) sm += __shfl_xor(sm, o);
            float inv = 1.f / sm;
#pragma unroll
            for (int nt = 0; nt < 8; nt++) accs[mt][nt][r] = sv[nt] * inv;
        }
    __syncthreads();    // q/k LDS reads done in all waves; safe to overlay P
#pragma unroll
    for (int mt = 0; mt < 2; mt++)
#pragma unroll
        for (int nt = 0; nt < 8; nt++)
#pragma unroll
            for (int r = 0; r < 4; r++)
                Ps[(R + mt * 16 + quad * 4 + r) * 136 + nt * 16 + lid] = f2b(accs[mt][nt][r]);
    __syncthreads();

    // O^T[d][q] = sum_k V^T[d][k] * P[q][k]; wave wv owns d-tile wv
    f32x4 acco[8];
#pragma unroll
    for (int nt = 0; nt < 8; nt++)
#pragma unroll
        for (int r = 0; r < 4; r++) acco[nt][r] = 0.f;
#pragma unroll
    for (int kq = 0; kq < 4; kq++) {
        int co = kq * 32 + quad * 8;
        short8 av = *(const short8*)&vt[(wv * 16 + lid) * 136 + co];
#pragma unroll
        for (int nt = 0; nt < 8; nt++) {
            short8 bp = *(const short8*)&Ps[(nt * 16 + lid) * 136 + co];
            acco[nt] = mfma16(av, bp, acco[nt]);
        }
    }
    size_t obase = (size_t)(b * 8192 + t * 128) * 1024 + h * 64;
#pragma unroll
    for (int nt = 0; nt < 8; nt++)
#pragma unroll
        for (int r = 0; r < 4; r++) {
            int d = wv * 16 + quad * 4 + r;
            int q = nt * 16 + lid;
            oat[obase + (size_t)q * 1024 + d] = f2b(acco[nt][r]);
        }
}

// ---------------------------------------------------------------------------
// K6c: per (b,h,t) chunk KV contribution: KVc[d][e] = sum_seq k[seq][d] v[seq][e]
__global__ __launch_bounds__(256) void k_kvchunk(const USH* __restrict__ qkv,
                                                 float* __restrict__ kvc) {
    __shared__ char smem[2 * 17408];
    USH* kt = (USH*)smem;                  // k^T [d][seq] stride 136
    USH* vt = (USH*)(smem + 17408);        // v^T [e][seq] stride 136
    int tid = threadIdx.x, wv = tid >> 6, lane = tid & 63, quad = lane >> 4, lid = lane & 15;
    int t = blockIdx.x, bh = blockIdx.y, b = bh >> 4, h = bh & 15;
    size_t base = ((size_t)(b * 8192 + t * 128)) * 3072 + h * 64;
    int r0 = tid >> 3, c0 = (tid & 7) * 8;
#pragma unroll
    for (int i = 0; i < 4; i++) {
        int r = i * 32 + r0;
        short8 kv = *(const short8*)(qkv + base + (size_t)r * 3072 + 1024 + c0);
        short8 vv = *(const short8*)(qkv + base + (size_t)r * 3072 + 2048 + c0);
        USH tk[8]; *(short8*)tk = kv;
        USH tv[8]; *(short8*)tv = vv;
#pragma unroll
        for (int j = 0; j < 8; j++) {
            kt[(c0 + j) * 136 + r] = tk[j];
            vt[(c0 + j) * 136 + r] = tv[j];
        }
    }
    __syncthreads();
    f32x4 acc[4];
#pragma unroll
    for (int nt = 0; nt < 4; nt++)
#pragma unroll
        for (int r = 0; r < 4; r++) acc[nt][r] = 0.f;
#pragma unroll
    for (int kq = 0; kq < 4; kq++) {
        int co = kq * 32 + quad * 8;
        short8 ak = *(const short8*)&kt[(wv * 16 + lid) * 136 + co];
#pragma unroll
        for (int nt = 0; nt < 4; nt++) {
            short8 bv = *(const short8*)&vt[(nt * 16 + lid) * 136 + co];
            acc[nt] = mfma16(ak, bv, acc[nt]);
        }
    }
    float* out = kvc + ((size_t)bh * 64 + t) * 4096;
#pragma unroll
    for (int nt = 0; nt < 4; nt++)
#pragma unroll
        for (int r = 0; r < 4; r++) {
            int d = wv * 16 + quad * 4 + r, e = nt * 16 + lid;
            out[d * 64 + e] = acc[nt][r];
        }
}

// ---------------------------------------------------------------------------
// K7: exclusive prefix over chunk axis of kvc — one chain per thread,
// 131072 independent chains of length 64 (deterministic, coalesced).
__global__ __launch_bounds__(256) void k_prefix(float* __restrict__ kvc) {
    int gid = blockIdx.x * 256 + threadIdx.x;   // 0 .. 131071
    int bh = gid >> 12, idx = gid & 4095;
    float* p = kvc + (size_t)bh * 64 * 4096 + idx;
    float a = 0.f;
    for (int t = 0; t < 64; t++) {
        float c = p[(size_t)t * 4096];
        p[(size_t)t * 4096] = a;
        a += c;
    }
}

// ---------------------------------------------------------------------------
// K8: o_inter[q][e] = sum_d q[q][d] * KVpre[d][e]; RMW-add into out_attn
__global__ __launch_bounds__(256) void k_ointer(const USH* __restrict__ qkv,
                                                const float* __restrict__ kvc,
                                                USH* __restrict__ oat) {
    __shared__ char smem[18432 + 9216];
    USH* qs = (USH*)smem;                  // [seq][d] stride 72
    USH* kvt = (USH*)(smem + 18432);       // KV^T [e][d] stride 72
    int tid = threadIdx.x, wv = tid >> 6, lane = tid & 63, quad = lane >> 4, lid = lane & 15;
    int t = blockIdx.x, bh = blockIdx.y, b = bh >> 4, h = bh & 15;
    size_t base = ((size_t)(b * 8192 + t * 128)) * 3072 + h * 64;
    int r0 = tid >> 3, c0 = (tid & 7) * 8;
#pragma unroll
    for (int i = 0; i < 4; i++) {
        int r = i * 32 + r0;
        short8 qv = *(const short8*)(qkv + base + (size_t)r * 3072 + c0);
        *(short8*)&qs[r * 72 + c0] = qv;
    }
    const float* kv = kvc + ((size_t)bh * 64 + t) * 4096;
#pragma unroll
    for (int j = 0; j < 16; j++) {
        int idx = j * 256 + tid;
        int d = idx >> 6, e = idx & 63;
        kvt[e * 72 + d] = f2b(kv[idx]);
    }
    __syncthreads();
    f32x4 acc[2][4];
#pragma unroll
    for (int mt = 0; mt < 2; mt++)
#pragma unroll
        for (int nt = 0; nt < 4; nt++)
#pragma unroll
            for (int r = 0; r < 4; r++) acc[mt][nt][r] = 0.f;
    int R = wv * 32;
#pragma unroll
    for (int kd = 0; kd < 2; kd++) {
        int co = kd * 32 + quad * 8;
        short8 a0 = *(const short8*)&qs[(R + lid) * 72 + co];
        short8 a1 = *(const short8*)&qs[(R + 16 + lid) * 72 + co];
#pragma unroll
        for (int nt = 0; nt < 4; nt++) {
            short8 bv = *(const short8*)&kvt[(nt * 16 + lid) * 72 + co];
            acc[0][nt] = mfma16(a0, bv, acc[0][nt]);
            acc[1][nt] = mfma16(a1, bv, acc[1][nt]);
        }
    }
#pragma unroll
    for (int mt = 0; mt < 2; mt++)
#pragma unroll
        for (int nt = 0; nt < 4; nt++)
#pragma unroll
            for (int r = 0; r < 4; r++) {
                int row = t * 128 + R + mt * 16 + quad * 4 + r;
                size_t idx = ((size_t)b * 8192 + row) * 1024 + h * 64 + nt * 16 + lid;
                float prev = b2f(oat[idx]);
                oat[idx] = f2b(prev + acc[mt][nt][r]);
            }
}

// ---------------------------------------------------------------------------
extern "C" void kernel_launch(void* const* d_in, const int* in_sizes, int n_in,
                              void* d_out, int out_size, void* d_ws, size_t ws_size,
                              hipStream_t stream) {
    const float* x      = (const float*)d_in[0];
    const float* cosp   = (const float*)d_in[1];
    const float* sinp   = (const float*)d_in[2];
    const float* qkv_w  = (const float*)d_in[3];
    const float* qkv_b  = (const float*)d_in[4];
    const float* qkv_nw = (const float*)d_in[5];
    const float* proj_w = (const float*)d_in[6];
    const float* proj_b = (const float*)d_in[7];
    const float* proj_nw= (const float*)d_in[8];
    const float* norm_w = (const float*)d_in[9];
    float* out = (float*)d_out;

    char* w = (char*)d_ws;
    float* sums    = (float*)(w + 0);                        // 8 B
    float* partials= (float*)(w + 64);                       // 512 f32 = 2048 B
    USH*   wq_qkv  = (USH*)(w + 4096);                       // 6,291,456 B
    USH*   wq_proj = (USH*)(w + 4096 + 6291456);             // 2,097,152 B
    float* inva    = (float*)(w + 8392704);                  // 65,536 B
    char*  R1      = w + 8458240;                            // 33,554,432 B
    char*  R2      = w + 8458240 + 33554432;                 // 33,554,432 B
    USH*   qkv     = (USH*)(w + 8458240 + 2ull * 33554432);  // 100,663,296 B
    USH*   xq      = (USH*)R1;       // stage-1 quantized activations
    USH*   oat     = (USH*)R1;       // out_attn (after xq is dead)
    float* kvc     = (float*)R2;     // chunk KV / exclusive prefix
    USH*   xq2     = (USH*)R2;       // stage-2 quantized activations (after kvc dead)

    k_wabs<<<dim3(256, 2), 256, 0, stream>>>(qkv_w, proj_w, partials);
    k_wsum<<<2, 256, 0, stream>>>(partials, sums);
    k_wquant<<<4096, 256, 0, stream>>>(qkv_w, proj_w, sums, wq_qkv, wq_proj);
    k_actq<<<16384, 256, 0, stream>>>(x, qkv_nw, xq, inva);
    k_gemm<true><<<dim3(12, 64), 512, 0, stream>>>(xq, wq_qkv, inva, &sums[0], 3145728.f,
                                                   qkv_b, cosp, sinp, (void*)qkv, 3072, 1024);
    k_attn_intra<<<dim3(64, 32), 256, 0, stream>>>(qkv, oat);
    k_kvchunk<<<dim3(64, 32), 256, 0, stream>>>(qkv, kvc);
    k_prefix<<<512, 256, 0, stream>>>(kvc);
    k_ointer<<<dim3(64, 32), 256, 0, stream>>>(qkv, kvc, oat);
    k_norm2q<<<16384, 256, 0, stream>>>(oat, norm_w, proj_nw, xq2, inva);
    k_gemm<false><<<dim3(4, 64), 512, 0, stream>>>(xq2, wq_proj, inva, &sums[1], 1048576.f,
                                                   proj_b, nullptr, nullptr, (void*)out, 1024, 1024);
    (void)in_sizes; (void)n_in; (void)out_size; (void)ws_size;
}

// Round 7
// 445.793 us; speedup vs baseline: 1.1047x; 1.1047x over previous
//
#include <hip/hip_runtime.h>

// ---------------------------------------------------------------------------
// LightningAttention2: bitlinear QKV -> RoPE -> chunked (softmax intra +
// linear inter) attention -> rms_norm -> bitlinear proj.
//
// Shapes: B=2, N=8192, DIM=1024, H=16, Dh=64, CHUNK=128, T=64. M = B*N = 16384.
//
// Numerics: activation quant -> integers in [-128,127]; weight quant ->
// {-1,0,1}. Both exact in bf16 => bf16 MFMA with fp32 accumulate is an EXACT
// integer GEMM (|sum| < 2^17 << 2^24). Dequant scales in fp32 epilogue.
//
// Determinism: NO float atomics. Fixed-order two-stage |w| reduction.
//
// R13 = R11 (passing, absmax 0.02539062; RoPE-in-GEMM-epilogue of R12
// REVERTED — it cost +82us of uncoalesced table loads + L2 refetch) with the
// GEMM switched to REGISTER-PREFETCH pipelining: tile t+1's fragments are
// ds_read into a second register set DURING tile t's 32 MFMAs. After each
// barrier a wave MFMAs immediately (no lgkm wait); its reads drain in the
// MFMA shadow. Staging distance t+3 (vmcnt(4), never 0 mid-loop); the
// pre-barrier lgkmcnt(0) is free (reads completed under 1242cyc of MFMA)
// and keeps buffer recycling WAR-safe. Same per-accumulator MFMA chain
// => bit-identical outputs (canary 0.02539062).
// ---------------------------------------------------------------------------

typedef unsigned short USH;
typedef __attribute__((ext_vector_type(8))) short short8;
typedef __attribute__((ext_vector_type(4))) float f32x4;
typedef __attribute__((ext_vector_type(4))) USH us4;

__device__ __forceinline__ float b2f(USH u) { return __uint_as_float(((unsigned)u) << 16); }
__device__ __forceinline__ USH f2b(float f) {
    unsigned u = __float_as_uint(f);
    u += 0x7fffu + ((u >> 16) & 1u);   // round-to-nearest-even
    return (USH)(u >> 16);
}
__device__ __forceinline__ f32x4 mfma16(short8 a, short8 b, f32x4 c) {
    return __builtin_amdgcn_mfma_f32_16x16x32_bf16(a, b, c, 0, 0, 0);
}
// async global->LDS, 16B per lane; LDS dest = wave-uniform base + lane*16
__device__ __forceinline__ void gload_lds16(const void* g, void* l) {
    __builtin_amdgcn_global_load_lds(
        (const __attribute__((address_space(1))) unsigned*)g,
        (__attribute__((address_space(3))) unsigned*)l, 16, 0, 0);
}

// block reductions over 256 threads (4 waves)
__device__ __forceinline__ float blk_sum(float v, float* red) {
#pragma unroll
    for (int o = 32; o; o >>= 1) v += __shfl_xor(v, o);
    __syncthreads();
    if ((threadIdx.x & 63) == 0) red[threadIdx.x >> 6] = v;
    __syncthreads();
    return red[0] + red[1] + red[2] + red[3];
}
__device__ __forceinline__ float blk_max(float v, float* red) {
#pragma unroll
    for (int o = 32; o; o >>= 1) v = fmaxf(v, __shfl_xor(v, o));
    __syncthreads();
    if ((threadIdx.x & 63) == 0) red[threadIdx.x >> 6] = v;
    __syncthreads();
    return fmaxf(fmaxf(red[0], red[1]), fmaxf(red[2], red[3]));
}

// ---------------------------------------------------------------------------
// K1a: per-block partial sums of |w| (deterministic — no atomics)
__global__ __launch_bounds__(256) void k_wabs(const float* __restrict__ qw,
                                              const float* __restrict__ pw,
                                              float* __restrict__ partials) {
    __shared__ float red[4];
    int which = blockIdx.y;
    const float4* p = (const float4*)(which ? pw : qw);
    int n4 = which ? (1024 * 1024 / 4) : (3072 * 1024 / 4);
    float s = 0.f;
    for (int i = blockIdx.x * 256 + threadIdx.x; i < n4; i += 256 * 256) {
        float4 v = p[i];
        s += fabsf(v.x) + fabsf(v.y) + fabsf(v.z) + fabsf(v.w);
    }
#pragma unroll
    for (int o = 32; o; o >>= 1) s += __shfl_xor(s, o);
    if ((threadIdx.x & 63) == 0) red[threadIdx.x >> 6] = s;
    __syncthreads();
    if (threadIdx.x == 0)
        partials[which * 256 + blockIdx.x] = red[0] + red[1] + red[2] + red[3];
}

// K1b: fixed-order reduction of 256 partials per matrix (deterministic)
__global__ __launch_bounds__(256) void k_wsum(const float* __restrict__ partials,
                                              float* __restrict__ sums) {
    __shared__ double red[4];
    int which = blockIdx.x;
    double v = (double)partials[which * 256 + threadIdx.x];
#pragma unroll
    for (int o = 32; o; o >>= 1) v += __shfl_xor(v, o);
    if ((threadIdx.x & 63) == 0) red[threadIdx.x >> 6] = v;
    __syncthreads();
    if (threadIdx.x == 0)
        sums[which] = (float)(red[0] + red[1] + red[2] + red[3]);
}

// ---------------------------------------------------------------------------
// K2: ternary-quantize both weight matrices to bf16 {-1,0,1}
__global__ __launch_bounds__(256) void k_wquant(const float* __restrict__ qw,
                                                const float* __restrict__ pw,
                                                const float* __restrict__ sums,
                                                USH* __restrict__ wqk, USH* __restrict__ wqp) {
    int id = blockIdx.x * 256 + threadIdx.x;   // 0 .. 1048575 (float4 units)
    float4 v; USH* dst; float sc;
    if (id < 786432) {
        v = ((const float4*)qw)[id];
        sc = 1.f / fmaxf(sums[0] * (1.f / 3145728.f), 1e-5f);
        dst = wqk + (size_t)id * 4;
    } else {
        int j = id - 786432;
        v = ((const float4*)pw)[j];
        sc = 1.f / fmaxf(sums[1] * (1.f / 1048576.f), 1e-5f);
        dst = wqp + (size_t)j * 4;
    }
    us4 o;
    o.x = f2b(fminf(fmaxf(rintf(v.x * sc), -1.f), 1.f));
    o.y = f2b(fminf(fmaxf(rintf(v.y * sc), -1.f), 1.f));
    o.z = f2b(fminf(fmaxf(rintf(v.z * sc), -1.f), 1.f));
    o.w = f2b(fminf(fmaxf(rintf(v.w * sc), -1.f), 1.f));
    *(us4*)dst = o;
}

// ---------------------------------------------------------------------------
// K3: RMS(eps_bit) * nw -> per-row int8 quant -> bf16 integers + inv_a
__global__ __launch_bounds__(256) void k_actq(const float* __restrict__ x,
                                              const float* __restrict__ nw,
                                              USH* __restrict__ xq, float* __restrict__ inva) {
    __shared__ float red[4];
    int row = blockIdx.x, tid = threadIdx.x;
    float4 v = ((const float4*)(x + (size_t)row * 1024))[tid];
    float4 w = ((const float4*)nw)[tid];
    float ss = v.x * v.x + v.y * v.y + v.z * v.z + v.w * v.w;
    ss = blk_sum(ss, red);
    float r1 = rsqrtf(ss * (1.f / 1024.f) + 1.1920929e-07f);
    float x0 = v.x * r1 * w.x, x1 = v.y * r1 * w.y, x2 = v.z * r1 * w.z, x3 = v.w * r1 * w.w;
    float am = fmaxf(fmaxf(fabsf(x0), fabsf(x1)), fmaxf(fabsf(x2), fabsf(x3)));
    am = blk_max(am, red);
    float amc = fmaxf(am, 1e-5f);
    float sc = 127.f / amc;
    us4 o;
    o.x = f2b(fminf(fmaxf(rintf(x0 * sc), -128.f), 127.f));
    o.y = f2b(fminf(fmaxf(rintf(x1 * sc), -128.f), 127.f));
    o.z = f2b(fminf(fmaxf(rintf(x2 * sc), -128.f), 127.f));
    o.w = f2b(fminf(fmaxf(rintf(x3 * sc), -128.f), 127.f));
    *(us4*)(xq + (size_t)row * 1024 + tid * 4) = o;
    if (tid == 0) inva[row] = amc * (1.f / 127.f);
}

// ---------------------------------------------------------------------------
// K9: rms_norm(out, norm_w) then bitlinear's own RMS(eps_bit)*proj_nw + quant
__global__ __launch_bounds__(256) void k_norm2q(const USH* __restrict__ oat,
                                                const float* __restrict__ nw,
                                                const float* __restrict__ pnw,
                                                USH* __restrict__ xq, float* __restrict__ inva) {
    __shared__ float red[4];
    int row = blockIdx.x, tid = threadIdx.x;
    us4 ov = *(const us4*)(oat + (size_t)row * 1024 + tid * 4);
    float o0 = b2f(ov.x), o1 = b2f(ov.y), o2 = b2f(ov.z), o3 = b2f(ov.w);
    float4 w = ((const float4*)nw)[tid];
    float4 pw = ((const float4*)pnw)[tid];
    float ss1 = blk_sum(o0 * o0 + o1 * o1 + o2 * o2 + o3 * o3, red);
    float r1 = rsqrtf(ss1 * (1.f / 1024.f) + 1e-6f);
    float y0 = o0 * r1 * w.x, y1 = o1 * r1 * w.y, y2 = o2 * r1 * w.z, y3 = o3 * r1 * w.w;
    float ss2 = blk_sum(y0 * y0 + y1 * y1 + y2 * y2 + y3 * y3, red);
    float r2 = rsqrtf(ss2 * (1.f / 1024.f) + 1.1920929e-07f);
    float z0 = y0 * r2 * pw.x, z1 = y1 * r2 * pw.y, z2 = y2 * r2 * pw.z, z3 = y3 * r2 * pw.w;
    float am = fmaxf(fmaxf(fabsf(z0), fabsf(z1)), fmaxf(fabsf(z2), fabsf(z3)));
    am = blk_max(am, red);
    float amc = fmaxf(am, 1e-5f);
    float sc = 127.f / amc;
    us4 q;
    q.x = f2b(fminf(fmaxf(rintf(z0 * sc), -128.f), 127.f));
    q.y = f2b(fminf(fmaxf(rintf(z1 * sc), -128.f), 127.f));
    q.z = f2b(fminf(fmaxf(rintf(z2 * sc), -128.f), 127.f));
    q.w = f2b(fminf(fmaxf(rintf(z3 * sc), -128.f), 127.f));
    *(us4*)(xq + (size_t)row * 1024 + tid * 4) = q;
    if (tid == 0) inva[row] = amc * (1.f / 127.f);
}

// ---------------------------------------------------------------------------
// GEMM R13: out[m][n] = (sum_k A[m][k]*W[n][k]) * inv_a[m] * wscale + bias[n]
// A: [M][K] bf16 ints; W: [N][K] bf16 ternary. K = 1024 (both calls).
//
// 256x256 tile, BK=32, 512 threads = 8 waves (2M x 4N), per-wave 128x64 out.
// LDS: 3 buffers x (A [256][32] + B [256][32]) = 96 KiB. Swizzle: pre-swizzled
// global source + same involution on ds_read (slot s -> s ^ ((r&3)^((r>>2)&1)),
// invariant under r+128 since it depends only on r&7 => single base pointer
// + uniform J1 = 128*K offset).
//
// REGISTER-PREFETCH pipeline: two fragment register sets (afA/bfA, afB/bfB).
// Iter t: vmcnt(4) lgkmcnt(0); barrier; issue 4 gloads tile t+3 -> buf t%3
// (tile t's LDS is dead — its frags were read in iter t-1, drained by this
// iter's lgkmcnt(0)); ds_read frags(t+1) from buf (t+1)%3 into the NEXT set
// (no wait — they drain under the MFMAs); 32 MFMA on the CURRENT set
// (operands ready since last iter => no lgkm stall after the barrier).
// vmcnt(0) only in the last 2 iters. Per-accumulator MFMA chain identical
// to R11 => bitwise identical outputs.
template <bool OUT_BF16>
__global__ __launch_bounds__(512, 2) void k_gemm(const USH* __restrict__ A, const USH* __restrict__ W,
                                                 const float* __restrict__ inva,
                                                 const float* __restrict__ wsum, float wcnt,
                                                 const float* __restrict__ bias,
                                                 void* __restrict__ out, int Nn, int K) {
    __shared__ __align__(16) USH lds[3 * 16384];   // per buf: A @ +0, B @ +8192 (USH units)
    const int tid = threadIdx.x;
    const int wv = tid >> 6, lane = tid & 63, quad = lane >> 4, lid = lane & 15;
    const int wr = wv >> 2, wc = wv & 3;

    // bijective XCD-aware swizzle (grids are 768 / 256 blocks: both %8 == 0)
    const int nbn = gridDim.x;
    const int nwg = nbn * gridDim.y;
    const int bid = blockIdx.y * nbn + blockIdx.x;
    const int swb = (bid & 7) * (nwg >> 3) + (bid >> 3);
    const int bn = swb % nbn, bm = swb / nbn;

    const int T = K >> 5;   // K-steps of 32 (T = 32)

    // staging source (pre-swizzled), j=0 rows; j=1 rows are +128 (same swizzle)
    const int r0s = wv * 16 + (lane >> 2);
    const int sw0 = (r0s & 3) ^ ((r0s >> 2) & 1);
    const int c0s = ((lane & 3) ^ sw0) * 8;
    const USH* ag0 = A + (size_t)(bm * 256 + r0s) * K + c0s;
    const USH* wg0 = W + (size_t)(bn * 256 + r0s) * K + c0s;
    const size_t J1 = (size_t)128 * K;

    // read-side swizzled slot: frag row = (multiple of 16) + lid
    const int sq = quad ^ ((lid & 3) ^ ((lid >> 2) & 1));
    const int arow = (wr * 128 + lid) * 32 + sq * 8;   // + mt*512
    const int brow = (wc * 64 + lid) * 32 + sq * 8;    // + nt*512 (B at +8192)

    f32x4 acc[8][4];
#pragma unroll
    for (int mt = 0; mt < 8; mt++)
#pragma unroll
        for (int nt = 0; nt < 4; nt++)
#pragma unroll
            for (int r = 0; r < 4; r++) acc[mt][nt][r] = 0.f;

    // prologue: stage tiles 0,1,2 (4 loads per tile per wave, tile-ordered)
#pragma unroll
    for (int t = 0; t < 3; t++) {
        USH* dst = &lds[t * 16384];
        gload_lds16(ag0 + t * 32,      &dst[wv * 512]);
        gload_lds16(ag0 + J1 + t * 32, &dst[(8 + wv) * 512]);
        gload_lds16(wg0 + t * 32,      &dst[8192 + wv * 512]);
        gload_lds16(wg0 + J1 + t * 32, &dst[8192 + (8 + wv) * 512]);
    }
    asm volatile("s_waitcnt vmcnt(8)" ::: "memory");   // tile 0 landed
    __builtin_amdgcn_s_barrier();
    __builtin_amdgcn_sched_barrier(0);

    short8 afA[8], bfA[4], afB[8], bfB[4];
#pragma unroll
    for (int mt = 0; mt < 8; mt++) afA[mt] = *(const short8*)&lds[arow + mt * 512];
#pragma unroll
    for (int nt = 0; nt < 4; nt++) bfA[nt] = *(const short8*)&lds[8192 + brow + nt * 512];

#define GITER(t, afC, bfC, afN, bfN)                                              \
    do {                                                                          \
        const USH* Rd = &lds[(((t) + 1) % 3) * 16384];                            \
        USH* Sd = &lds[((t) % 3) * 16384];                                        \
        if ((t) + 2 < T) asm volatile("s_waitcnt vmcnt(4) lgkmcnt(0)" ::: "memory"); \
        else             asm volatile("s_waitcnt vmcnt(0) lgkmcnt(0)" ::: "memory"); \
        __builtin_amdgcn_s_barrier();                                             \
        __builtin_amdgcn_sched_barrier(0);                                        \
        if ((t) + 3 < T) {                                                        \
            gload_lds16(ag0 + ((t) + 3) * 32,      &Sd[wv * 512]);                \
            gload_lds16(ag0 + J1 + ((t) + 3) * 32, &Sd[(8 + wv) * 512]);          \
            gload_lds16(wg0 + ((t) + 3) * 32,      &Sd[8192 + wv * 512]);         \
            gload_lds16(wg0 + J1 + ((t) + 3) * 32, &Sd[8192 + (8 + wv) * 512]);   \
        }                                                                         \
        if ((t) + 1 < T) {                                                        \
            _Pragma("unroll")                                                     \
            for (int mt_ = 0; mt_ < 8; mt_++)                                     \
                afN[mt_] = *(const short8*)&Rd[arow + mt_ * 512];                 \
            _Pragma("unroll")                                                     \
            for (int nt_ = 0; nt_ < 4; nt_++)                                     \
                bfN[nt_] = *(const short8*)&Rd[8192 + brow + nt_ * 512];          \
        }                                                                         \
        __builtin_amdgcn_s_setprio(1);                                            \
        _Pragma("unroll")                                                         \
        for (int mt_ = 0; mt_ < 8; mt_++)                                         \
            _Pragma("unroll")                                                     \
            for (int nt_ = 0; nt_ < 4; nt_++)                                     \
                acc[mt_][nt_] = mfma16(afC[mt_], bfC[nt_], acc[mt_][nt_]);        \
        __builtin_amdgcn_s_setprio(0);                                            \
    } while (0)

    for (int tt = 0; tt < T; tt += 2) {
        GITER(tt,     afA, bfA, afB, bfB);
        GITER(tt + 1, afB, bfB, afA, bfA);
    }
#undef GITER

    float wm = fmaxf(wsum[0] * (1.f / wcnt), 1e-5f);
#pragma unroll
    for (int mt = 0; mt < 8; mt++)
#pragma unroll
        for (int r = 0; r < 4; r++) {
            int rowg = bm * 256 + wr * 128 + mt * 16 + quad * 4 + r;
            float ia = inva[rowg] * wm;
#pragma unroll
            for (int nt = 0; nt < 4; nt++) {
                int colg = bn * 256 + wc * 64 + nt * 16 + lid;
                float v = acc[mt][nt][r] * ia + bias[colg];
                if (OUT_BF16) ((USH*)out)[(size_t)rowg * Nn + colg] = f2b(v);
                else ((float*)out)[(size_t)rowg * Nn + colg] = v;
            }
        }
}

// ---------------------------------------------------------------------------
// K5: RoPE in place on q,k halves of qkv buffer (interleaved pairs)
__global__ __launch_bounds__(256) void k_rope(USH* __restrict__ qkv,
                                              const float* __restrict__ cs,
                                              const float* __restrict__ sn) {
    int id = blockIdx.x * 256 + threadIdx.x;    // < 16384*1024 pairs
    int rowm = id >> 10, p = id & 1023;
    int part = p >> 9, pi = p & 511;
    int h = pi >> 5, i = pi & 31;
    int n = rowm & 8191;
    size_t a = (size_t)rowm * 3072 + part * 1024 + h * 64 + 2 * i;
    float c = cs[n * 32 + i], s = sn[n * 32 + i];
    unsigned* pp = (unsigned*)(qkv + a);
    unsigned u = *pp;
    float x0 = b2f((USH)(u & 0xffff)), x1 = b2f((USH)(u >> 16));
    float y0 = x0 * c - x1 * s;
    float y1 = x1 * c + x0 * s;
    *pp = (unsigned)f2b(y0) | ((unsigned)f2b(y1) << 16);
}

// ---------------------------------------------------------------------------
// K6: per (b,h,t) intra-chunk: S=q k^T*scale, causal softmax, O^T = V^T P^T.
// Writes o_intra (bf16) to out_attn.  LDS: 54272 B.
__global__ __launch_bounds__(256) void k_attn_intra(const USH* __restrict__ qkv,
                                                    USH* __restrict__ oat) {
    __shared__ char smem[36864 + 17408];
    USH* qs = (USH*)smem;                 // [seq][d]  stride 72
    USH* kqs = qs + 128 * 72;             // [seq][d]  stride 72
    USH* Ps = (USH*)smem;                 // overlay: P [seqq][seqk] stride 136
    USH* vt = (USH*)(smem + 36864);       // V^T [d][seq] stride 136
    int tid = threadIdx.x, wv = tid >> 6, lane = tid & 63, quad = lane >> 4, lid = lane & 15;
    int t = blockIdx.x, bh = blockIdx.y, b = bh >> 4, h = bh & 15;
    size_t base = ((size_t)(b * 8192 + t * 128)) * 3072 + h * 64;
    int r0 = tid >> 3, c0 = (tid & 7) * 8;
#pragma unroll
    for (int i = 0; i < 4; i++) {
        int r = i * 32 + r0;
        short8 qv = *(const short8*)(qkv + base + (size_t)r * 3072 + c0);
        short8 kv = *(const short8*)(qkv + base + (size_t)r * 3072 + 1024 + c0);
        short8 vv = *(const short8*)(qkv + base + (size_t)r * 3072 + 2048 + c0);
        *(short8*)&qs[r * 72 + c0] = qv;
        *(short8*)&kqs[r * 72 + c0] = kv;
        USH tmp[8]; *(short8*)tmp = vv;
#pragma unroll
        for (int j = 0; j < 8; j++) vt[(c0 + j) * 136 + r] = tmp[j];
    }
    __syncthreads();

    f32x4 accs[2][8];
#pragma unroll
    for (int mt = 0; mt < 2; mt++)
#pragma unroll
        for (int nt = 0; nt < 8; nt++)
#pragma unroll
            for (int r = 0; r < 4; r++) accs[mt][nt][r] = 0.f;
    int R = wv * 32;
#pragma unroll
    for (int ksx = 0; ksx < 2; ksx++) {
        int co = ksx * 32 + quad * 8;
        short8 af0 = *(const short8*)&qs[(R + lid) * 72 + co];
        short8 af1 = *(const short8*)&qs[(R + 16 + lid) * 72 + co];
        short8 bf[8];
#pragma unroll
        for (int nt = 0; nt < 8; nt++) bf[nt] = *(const short8*)&kqs[(nt * 16 + lid) * 72 + co];
#pragma unroll
        for (int nt = 0; nt < 8; nt++) {
            accs[0][nt] = mfma16(af0, bf[nt], accs[0][nt]);
            accs[1][nt] = mfma16(af1, bf[nt], accs[1][nt]);
        }
    }
    // softmax (rows owned within wave; reduce across 16 lanes of each quad)
#pragma unroll
    for (int mt = 0; mt < 2; mt++)
#pragma unroll
        for (int r = 0; r < 4; r++) {
            int row = R + mt * 16 + quad * 4 + r;
            float sv[8];
            float mx = -3.0e38f;
#pragma unroll
            for (int nt = 0; nt < 8; nt++) {
                int col = nt * 16 + lid;
                float v = accs[mt][nt][r] * 0.125f;
                sv[nt] = (col <= row) ? v : -3.0e38f;
                mx = fmaxf(mx, sv[nt]);
            }
#pragma unroll
            for (int o = 8; o; o >>= 1) mx = fmaxf(mx, __shfl_xor(mx, o));
            float sm = 0.f;
#pragma unroll
            for (int nt = 0; nt < 8; nt++) {
                float e = (sv[nt] > -1.0e38f) ? __expf(sv[nt] - mx) : 0.f;
                sv[nt] = e; sm += e;
            }
#pragma unroll
            for (int o = 8; o; o >>= 1) sm += __shfl_xor(sm, o);
            float inv = 1.f / sm;
#pragma unroll
            for (int nt = 0; nt < 8; nt++) accs[mt][nt][r] = sv[nt] * inv;
        }
    __syncthreads();    // q/k LDS reads done in all waves; safe to overlay P
#pragma unroll
    for (int mt = 0; mt < 2; mt++)
#pragma unroll
        for (int nt = 0; nt < 8; nt++)
#pragma unroll
            for (int r = 0; r < 4; r++)
                Ps[(R + mt * 16 + quad * 4 + r) * 136 + nt * 16 + lid] = f2b(accs[mt][nt][r]);
    __syncthreads();

    // O^T[d][q] = sum_k V^T[d][k] * P[q][k]; wave wv owns d-tile wv
    f32x4 acco[8];
#pragma unroll
    for (int nt = 0; nt < 8; nt++)
#pragma unroll
        for (int r = 0; r < 4; r++) acco[nt][r] = 0.f;
#pragma unroll
    for (int kq = 0; kq < 4; kq++) {
        int co = kq * 32 + quad * 8;
        short8 av = *(const short8*)&vt[(wv * 16 + lid) * 136 + co];
#pragma unroll
        for (int nt = 0; nt < 8; nt++) {
            short8 bp = *(const short8*)&Ps[(nt * 16 + lid) * 136 + co];
            acco[nt] = mfma16(av, bp, acco[nt]);
        }
    }
    size_t obase = (size_t)(b * 8192 + t * 128) * 1024 + h * 64;
#pragma unroll
    for (int nt = 0; nt < 8; nt++)
#pragma unroll
        for (int r = 0; r < 4; r++) {
            int d = wv * 16 + quad * 4 + r;
            int q = nt * 16 + lid;
            oat[obase + (size_t)q * 1024 + d] = f2b(acco[nt][r]);
        }
}

// ---------------------------------------------------------------------------
// K6c: per (b,h,t) chunk KV contribution: KVc[d][e] = sum_seq k[seq][d] v[seq][e]
__global__ __launch_bounds__(256) void k_kvchunk(const USH* __restrict__ qkv,
                                                 float* __restrict__ kvc) {
    __shared__ char smem[2 * 17408];
    USH* kt = (USH*)smem;                  // k^T [d][seq] stride 136
    USH* vt = (USH*)(smem + 17408);        // v^T [e][seq] stride 136
    int tid = threadIdx.x, wv = tid >> 6, lane = tid & 63, quad = lane >> 4, lid = lane & 15;
    int t = blockIdx.x, bh = blockIdx.y, b = bh >> 4, h = bh & 15;
    size_t base = ((size_t)(b * 8192 + t * 128)) * 3072 + h * 64;
    int r0 = tid >> 3, c0 = (tid & 7) * 8;
#pragma unroll
    for (int i = 0; i < 4; i++) {
        int r = i * 32 + r0;
        short8 kv = *(const short8*)(qkv + base + (size_t)r * 3072 + 1024 + c0);
        short8 vv = *(const short8*)(qkv + base + (size_t)r * 3072 + 2048 + c0);
        USH tk[8]; *(short8*)tk = kv;
        USH tv[8]; *(short8*)tv = vv;
#pragma unroll
        for (int j = 0; j < 8; j++) {
            kt[(c0 + j) * 136 + r] = tk[j];
            vt[(c0 + j) * 136 + r] = tv[j];
        }
    }
    __syncthreads();
    f32x4 acc[4];
#pragma unroll
    for (int nt = 0; nt < 4; nt++)
#pragma unroll
        for (int r = 0; r < 4; r++) acc[nt][r] = 0.f;
#pragma unroll
    for (int kq = 0; kq < 4; kq++) {
        int co = kq * 32 + quad * 8;
        short8 ak = *(const short8*)&kt[(wv * 16 + lid) * 136 + co];
#pragma unroll
        for (int nt = 0; nt < 4; nt++) {
            short8 bv = *(const short8*)&vt[(nt * 16 + lid) * 136 + co];
            acc[nt] = mfma16(ak, bv, acc[nt]);
        }
    }
    float* out = kvc + ((size_t)bh * 64 + t) * 4096;
#pragma unroll
    for (int nt = 0; nt < 4; nt++)
#pragma unroll
        for (int r = 0; r < 4; r++) {
            int d = wv * 16 + quad * 4 + r, e = nt * 16 + lid;
            out[d * 64 + e] = acc[nt][r];
        }
}

// ---------------------------------------------------------------------------
// K7: exclusive prefix over chunk axis of kvc — one chain per thread,
// 131072 independent chains of length 64 (deterministic, coalesced).
__global__ __launch_bounds__(256) void k_prefix(float* __restrict__ kvc) {
    int gid = blockIdx.x * 256 + threadIdx.x;   // 0 .. 131071
    int bh = gid >> 12, idx = gid & 4095;
    float* p = kvc + (size_t)bh * 64 * 4096 + idx;
    float a = 0.f;
    for (int t = 0; t < 64; t++) {
        float c = p[(size_t)t * 4096];
        p[(size_t)t * 4096] = a;
        a += c;
    }
}

// ---------------------------------------------------------------------------
// K8: o_inter[q][e] = sum_d q[q][d] * KVpre[d][e]; RMW-add into out_attn
__global__ __launch_bounds__(256) void k_ointer(const USH* __restrict__ qkv,
                                                const float* __restrict__ kvc,
                                                USH* __restrict__ oat) {
    __shared__ char smem[18432 + 9216];
    USH* qs = (USH*)smem;                  // [seq][d] stride 72
    USH* kvt = (USH*)(smem + 18432);       // KV^T [e][d] stride 72
    int tid = threadIdx.x, wv = tid >> 6, lane = tid & 63, quad = lane >> 4, lid = lane & 15;
    int t = blockIdx.x, bh = blockIdx.y, b = bh >> 4, h = bh & 15;
    size_t base = ((size_t)(b * 8192 + t * 128)) * 3072 + h * 64;
    int r0 = tid >> 3, c0 = (tid & 7) * 8;
#pragma unroll
    for (int i = 0; i < 4; i++) {
        int r = i * 32 + r0;
        short8 qv = *(const short8*)(qkv + base + (size_t)r * 3072 + c0);
        *(short8*)&qs[r * 72 + c0] = qv;
    }
    const float* kv = kvc + ((size_t)bh * 64 + t) * 4096;
#pragma unroll
    for (int j = 0; j < 16; j++) {
        int idx = j * 256 + tid;
        int d = idx >> 6, e = idx & 63;
        kvt[e * 72 + d] = f2b(kv[idx]);
    }
    __syncthreads();
    f32x4 acc[2][4];
#pragma unroll
    for (int mt = 0; mt < 2; mt++)
#pragma unroll
        for (int nt = 0; nt < 4; nt++)
#pragma unroll
            for (int r = 0; r < 4; r++) acc[mt][nt][r] = 0.f;
    int R = wv * 32;
#pragma unroll
    for (int kd = 0; kd < 2; kd++) {
        int co = kd * 32 + quad * 8;
        short8 a0 = *(const short8*)&qs[(R + lid) * 72 + co];
        short8 a1 = *(const short8*)&qs[(R + 16 + lid) * 72 + co];
#pragma unroll
        for (int nt = 0; nt < 4; nt++) {
            short8 bv = *(const short8*)&kvt[(nt * 16 + lid) * 72 + co];
            acc[0][nt] = mfma16(a0, bv, acc[0][nt]);
            acc[1][nt] = mfma16(a1, bv, acc[1][nt]);
        }
    }
#pragma unroll
    for (int mt = 0; mt < 2; mt++)
#pragma unroll
        for (int nt = 0; nt < 4; nt++)
#pragma unroll
            for (int r = 0; r < 4; r++) {
                int row = t * 128 + R + mt * 16 + quad * 4 + r;
                size_t idx = ((size_t)b * 8192 + row) * 1024 + h * 64 + nt * 16 + lid;
                float prev = b2f(oat[idx]);
                oat[idx] = f2b(prev + acc[mt][nt][r]);
            }
}

// ---------------------------------------------------------------------------
extern "C" void kernel_launch(void* const* d_in, const int* in_sizes, int n_in,
                              void* d_out, int out_size, void* d_ws, size_t ws_size,
                              hipStream_t stream) {
    const float* x      = (const float*)d_in[0];
    const float* cosp   = (const float*)d_in[1];
    const float* sinp   = (const float*)d_in[2];
    const float* qkv_w  = (const float*)d_in[3];
    const float* qkv_b  = (const float*)d_in[4];
    const float* qkv_nw = (const float*)d_in[5];
    const float* proj_w = (const float*)d_in[6];
    const float* proj_b = (const float*)d_in[7];
    const float* proj_nw= (const float*)d_in[8];
    const float* norm_w = (const float*)d_in[9];
    float* out = (float*)d_out;

    char* w = (char*)d_ws;
    float* sums    = (float*)(w + 0);                        // 8 B
    float* partials= (float*)(w + 64);                       // 512 f32 = 2048 B
    USH*   wq_qkv  = (USH*)(w + 4096);                       // 6,291,456 B
    USH*   wq_proj = (USH*)(w + 4096 + 6291456);             // 2,097,152 B
    float* inva    = (float*)(w + 8392704);                  // 65,536 B
    char*  R1      = w + 8458240;                            // 33,554,432 B
    char*  R2      = w + 8458240 + 33554432;                 // 33,554,432 B
    USH*   qkv     = (USH*)(w + 8458240 + 2ull * 33554432);  // 100,663,296 B
    USH*   xq      = (USH*)R1;       // stage-1 quantized activations
    USH*   oat     = (USH*)R1;       // out_attn (after xq is dead)
    float* kvc     = (float*)R2;     // chunk KV / exclusive prefix
    USH*   xq2     = (USH*)R2;       // stage-2 quantized activations (after kvc dead)

    k_wabs<<<dim3(256, 2), 256, 0, stream>>>(qkv_w, proj_w, partials);
    k_wsum<<<2, 256, 0, stream>>>(partials, sums);
    k_wquant<<<4096, 256, 0, stream>>>(qkv_w, proj_w, sums, wq_qkv, wq_proj);
    k_actq<<<16384, 256, 0, stream>>>(x, qkv_nw, xq, inva);
    k_gemm<true><<<dim3(12, 64), 512, 0, stream>>>(xq, wq_qkv, inva, &sums[0], 3145728.f,
                                                   qkv_b, (void*)qkv, 3072, 1024);
    k_rope<<<65536, 256, 0, stream>>>(qkv, cosp, sinp);
    k_attn_intra<<<dim3(64, 32), 256, 0, stream>>>(qkv, oat);
    k_kvchunk<<<dim3(64, 32), 256, 0, stream>>>(qkv, kvc);
    k_prefix<<<512, 256, 0, stream>>>(kvc);
    k_ointer<<<dim3(64, 32), 256, 0, stream>>>(qkv, kvc, oat);
    k_norm2q<<<16384, 256, 0, stream>>>(oat, norm_w, proj_nw, xq2, inva);
    k_gemm<false><<<dim3(4, 64), 512, 0, stream>>>(xq2, wq_proj, inva, &sums[1], 1048576.f,
                                                   proj_b, (void*)out, 1024, 1024);
    (void)in_sizes; (void)n_in; (void)out_size; (void)ws_size;
}

// Round 8
// 423.247 us; speedup vs baseline: 1.1635x; 1.0533x over previous
//
#include <hip/hip_runtime.h>

// ---------------------------------------------------------------------------
// LightningAttention2: bitlinear QKV -> RoPE -> chunked (softmax intra +
// linear inter) attention -> rms_norm -> bitlinear proj.
//
// Shapes: B=2, N=8192, DIM=1024, H=16, Dh=64, CHUNK=128, T=64. M = B*N = 16384.
//
// Numerics: activation quant -> integers in [-128,127]; weight quant ->
// {-1,0,1}. Both exact in bf16 => bf16 MFMA with fp32 accumulate is an EXACT
// integer GEMM (|sum| < 2^17 << 2^24). Dequant scales in fp32 epilogue.
//
// Determinism: NO float atomics. Fixed-order two-stage |w| reduction.
//
// R14 = R13 (passing, absmax 0.02539062; GEMM untouched — 4 schedule
// variants all 122us/35% MfmaUtil, structure ceiling accepted) with two
// arithmetic-preserving pipeline wins:
//  (a) k_attn_intra + k_kvchunk FUSED: both were per-(b,h,t) blocks loading
//      the same k,v chunk (~64 MB redundant read). One load pass builds
//      qs,kqs (row-major) + kt,vt (transposed); intra path verbatim; then
//      kvchunk's MFMAs appended (kt/vt live outside the P overlay).
//      LDS 71680 B (2 blocks/CU, unchanged vs intra). Bit-identical.
//  (b) k_rope vectorized 4x: one thread per 4 pairs (short8 RW + float4
//      tables), same per-pair fp32 math/rounding. Bit-identical.
// Canary: absmax must stay exactly 0.02539062.
// ---------------------------------------------------------------------------

typedef unsigned short USH;
typedef __attribute__((ext_vector_type(8))) short short8;
typedef __attribute__((ext_vector_type(4))) float f32x4;
typedef __attribute__((ext_vector_type(4))) USH us4;

__device__ __forceinline__ float b2f(USH u) { return __uint_as_float(((unsigned)u) << 16); }
__device__ __forceinline__ USH f2b(float f) {
    unsigned u = __float_as_uint(f);
    u += 0x7fffu + ((u >> 16) & 1u);   // round-to-nearest-even
    return (USH)(u >> 16);
}
__device__ __forceinline__ f32x4 mfma16(short8 a, short8 b, f32x4 c) {
    return __builtin_amdgcn_mfma_f32_16x16x32_bf16(a, b, c, 0, 0, 0);
}
// async global->LDS, 16B per lane; LDS dest = wave-uniform base + lane*16
__device__ __forceinline__ void gload_lds16(const void* g, void* l) {
    __builtin_amdgcn_global_load_lds(
        (const __attribute__((address_space(1))) unsigned*)g,
        (__attribute__((address_space(3))) unsigned*)l, 16, 0, 0);
}

// block reductions over 256 threads (4 waves)
__device__ __forceinline__ float blk_sum(float v, float* red) {
#pragma unroll
    for (int o = 32; o; o >>= 1) v += __shfl_xor(v, o);
    __syncthreads();
    if ((threadIdx.x & 63) == 0) red[threadIdx.x >> 6] = v;
    __syncthreads();
    return red[0] + red[1] + red[2] + red[3];
}
__device__ __forceinline__ float blk_max(float v, float* red) {
#pragma unroll
    for (int o = 32; o; o >>= 1) v = fmaxf(v, __shfl_xor(v, o));
    __syncthreads();
    if ((threadIdx.x & 63) == 0) red[threadIdx.x >> 6] = v;
    __syncthreads();
    return fmaxf(fmaxf(red[0], red[1]), fmaxf(red[2], red[3]));
}

// ---------------------------------------------------------------------------
// K1a: per-block partial sums of |w| (deterministic — no atomics)
__global__ __launch_bounds__(256) void k_wabs(const float* __restrict__ qw,
                                              const float* __restrict__ pw,
                                              float* __restrict__ partials) {
    __shared__ float red[4];
    int which = blockIdx.y;
    const float4* p = (const float4*)(which ? pw : qw);
    int n4 = which ? (1024 * 1024 / 4) : (3072 * 1024 / 4);
    float s = 0.f;
    for (int i = blockIdx.x * 256 + threadIdx.x; i < n4; i += 256 * 256) {
        float4 v = p[i];
        s += fabsf(v.x) + fabsf(v.y) + fabsf(v.z) + fabsf(v.w);
    }
#pragma unroll
    for (int o = 32; o; o >>= 1) s += __shfl_xor(s, o);
    if ((threadIdx.x & 63) == 0) red[threadIdx.x >> 6] = s;
    __syncthreads();
    if (threadIdx.x == 0)
        partials[which * 256 + blockIdx.x] = red[0] + red[1] + red[2] + red[3];
}

// K1b: fixed-order reduction of 256 partials per matrix (deterministic)
__global__ __launch_bounds__(256) void k_wsum(const float* __restrict__ partials,
                                              float* __restrict__ sums) {
    __shared__ double red[4];
    int which = blockIdx.x;
    double v = (double)partials[which * 256 + threadIdx.x];
#pragma unroll
    for (int o = 32; o; o >>= 1) v += __shfl_xor(v, o);
    if ((threadIdx.x & 63) == 0) red[threadIdx.x >> 6] = v;
    __syncthreads();
    if (threadIdx.x == 0)
        sums[which] = (float)(red[0] + red[1] + red[2] + red[3]);
}

// ---------------------------------------------------------------------------
// K2: ternary-quantize both weight matrices to bf16 {-1,0,1}
__global__ __launch_bounds__(256) void k_wquant(const float* __restrict__ qw,
                                                const float* __restrict__ pw,
                                                const float* __restrict__ sums,
                                                USH* __restrict__ wqk, USH* __restrict__ wqp) {
    int id = blockIdx.x * 256 + threadIdx.x;   // 0 .. 1048575 (float4 units)
    float4 v; USH* dst; float sc;
    if (id < 786432) {
        v = ((const float4*)qw)[id];
        sc = 1.f / fmaxf(sums[0] * (1.f / 3145728.f), 1e-5f);
        dst = wqk + (size_t)id * 4;
    } else {
        int j = id - 786432;
        v = ((const float4*)pw)[j];
        sc = 1.f / fmaxf(sums[1] * (1.f / 1048576.f), 1e-5f);
        dst = wqp + (size_t)j * 4;
    }
    us4 o;
    o.x = f2b(fminf(fmaxf(rintf(v.x * sc), -1.f), 1.f));
    o.y = f2b(fminf(fmaxf(rintf(v.y * sc), -1.f), 1.f));
    o.z = f2b(fminf(fmaxf(rintf(v.z * sc), -1.f), 1.f));
    o.w = f2b(fminf(fmaxf(rintf(v.w * sc), -1.f), 1.f));
    *(us4*)dst = o;
}

// ---------------------------------------------------------------------------
// K3: RMS(eps_bit) * nw -> per-row int8 quant -> bf16 integers + inv_a
__global__ __launch_bounds__(256) void k_actq(const float* __restrict__ x,
                                              const float* __restrict__ nw,
                                              USH* __restrict__ xq, float* __restrict__ inva) {
    __shared__ float red[4];
    int row = blockIdx.x, tid = threadIdx.x;
    float4 v = ((const float4*)(x + (size_t)row * 1024))[tid];
    float4 w = ((const float4*)nw)[tid];
    float ss = v.x * v.x + v.y * v.y + v.z * v.z + v.w * v.w;
    ss = blk_sum(ss, red);
    float r1 = rsqrtf(ss * (1.f / 1024.f) + 1.1920929e-07f);
    float x0 = v.x * r1 * w.x, x1 = v.y * r1 * w.y, x2 = v.z * r1 * w.z, x3 = v.w * r1 * w.w;
    float am = fmaxf(fmaxf(fabsf(x0), fabsf(x1)), fmaxf(fabsf(x2), fabsf(x3)));
    am = blk_max(am, red);
    float amc = fmaxf(am, 1e-5f);
    float sc = 127.f / amc;
    us4 o;
    o.x = f2b(fminf(fmaxf(rintf(x0 * sc), -128.f), 127.f));
    o.y = f2b(fminf(fmaxf(rintf(x1 * sc), -128.f), 127.f));
    o.z = f2b(fminf(fmaxf(rintf(x2 * sc), -128.f), 127.f));
    o.w = f2b(fminf(fmaxf(rintf(x3 * sc), -128.f), 127.f));
    *(us4*)(xq + (size_t)row * 1024 + tid * 4) = o;
    if (tid == 0) inva[row] = amc * (1.f / 127.f);
}

// ---------------------------------------------------------------------------
// K9: rms_norm(out, norm_w) then bitlinear's own RMS(eps_bit)*proj_nw + quant
__global__ __launch_bounds__(256) void k_norm2q(const USH* __restrict__ oat,
                                                const float* __restrict__ nw,
                                                const float* __restrict__ pnw,
                                                USH* __restrict__ xq, float* __restrict__ inva) {
    __shared__ float red[4];
    int row = blockIdx.x, tid = threadIdx.x;
    us4 ov = *(const us4*)(oat + (size_t)row * 1024 + tid * 4);
    float o0 = b2f(ov.x), o1 = b2f(ov.y), o2 = b2f(ov.z), o3 = b2f(ov.w);
    float4 w = ((const float4*)nw)[tid];
    float4 pw = ((const float4*)pnw)[tid];
    float ss1 = blk_sum(o0 * o0 + o1 * o1 + o2 * o2 + o3 * o3, red);
    float r1 = rsqrtf(ss1 * (1.f / 1024.f) + 1e-6f);
    float y0 = o0 * r1 * w.x, y1 = o1 * r1 * w.y, y2 = o2 * r1 * w.z, y3 = o3 * r1 * w.w;
    float ss2 = blk_sum(y0 * y0 + y1 * y1 + y2 * y2 + y3 * y3, red);
    float r2 = rsqrtf(ss2 * (1.f / 1024.f) + 1.1920929e-07f);
    float z0 = y0 * r2 * pw.x, z1 = y1 * r2 * pw.y, z2 = y2 * r2 * pw.z, z3 = y3 * r2 * pw.w;
    float am = fmaxf(fmaxf(fabsf(z0), fabsf(z1)), fmaxf(fabsf(z2), fabsf(z3)));
    am = blk_max(am, red);
    float amc = fmaxf(am, 1e-5f);
    float sc = 127.f / amc;
    us4 q;
    q.x = f2b(fminf(fmaxf(rintf(z0 * sc), -128.f), 127.f));
    q.y = f2b(fminf(fmaxf(rintf(z1 * sc), -128.f), 127.f));
    q.z = f2b(fminf(fmaxf(rintf(z2 * sc), -128.f), 127.f));
    q.w = f2b(fminf(fmaxf(rintf(z3 * sc), -128.f), 127.f));
    *(us4*)(xq + (size_t)row * 1024 + tid * 4) = q;
    if (tid == 0) inva[row] = amc * (1.f / 127.f);
}

// ---------------------------------------------------------------------------
// GEMM (R13 form, passing): out[m][n] = (sum A*W) * inv_a[m] * wscale + bias.
// 256x256 tile, BK=32, 8 waves, triple-buffered 96 KiB LDS, register-prefetch
// pipeline, counted vmcnt(4), XOR swizzle, XCD block swizzle.
template <bool OUT_BF16>
__global__ __launch_bounds__(512, 2) void k_gemm(const USH* __restrict__ A, const USH* __restrict__ W,
                                                 const float* __restrict__ inva,
                                                 const float* __restrict__ wsum, float wcnt,
                                                 const float* __restrict__ bias,
                                                 void* __restrict__ out, int Nn, int K) {
    __shared__ __align__(16) USH lds[3 * 16384];   // per buf: A @ +0, B @ +8192 (USH units)
    const int tid = threadIdx.x;
    const int wv = tid >> 6, lane = tid & 63, quad = lane >> 4, lid = lane & 15;
    const int wr = wv >> 2, wc = wv & 3;

    // bijective XCD-aware swizzle (grids are 768 / 256 blocks: both %8 == 0)
    const int nbn = gridDim.x;
    const int nwg = nbn * gridDim.y;
    const int bid = blockIdx.y * nbn + blockIdx.x;
    const int swb = (bid & 7) * (nwg >> 3) + (bid >> 3);
    const int bn = swb % nbn, bm = swb / nbn;

    const int T = K >> 5;   // K-steps of 32 (T = 32)

    // staging source (pre-swizzled), j=0 rows; j=1 rows are +128 (same swizzle)
    const int r0s = wv * 16 + (lane >> 2);
    const int sw0 = (r0s & 3) ^ ((r0s >> 2) & 1);
    const int c0s = ((lane & 3) ^ sw0) * 8;
    const USH* ag0 = A + (size_t)(bm * 256 + r0s) * K + c0s;
    const USH* wg0 = W + (size_t)(bn * 256 + r0s) * K + c0s;
    const size_t J1 = (size_t)128 * K;

    // read-side swizzled slot: frag row = (multiple of 16) + lid
    const int sq = quad ^ ((lid & 3) ^ ((lid >> 2) & 1));
    const int arow = (wr * 128 + lid) * 32 + sq * 8;   // + mt*512
    const int brow = (wc * 64 + lid) * 32 + sq * 8;    // + nt*512 (B at +8192)

    f32x4 acc[8][4];
#pragma unroll
    for (int mt = 0; mt < 8; mt++)
#pragma unroll
        for (int nt = 0; nt < 4; nt++)
#pragma unroll
            for (int r = 0; r < 4; r++) acc[mt][nt][r] = 0.f;

    // prologue: stage tiles 0,1,2 (4 loads per tile per wave, tile-ordered)
#pragma unroll
    for (int t = 0; t < 3; t++) {
        USH* dst = &lds[t * 16384];
        gload_lds16(ag0 + t * 32,      &dst[wv * 512]);
        gload_lds16(ag0 + J1 + t * 32, &dst[(8 + wv) * 512]);
        gload_lds16(wg0 + t * 32,      &dst[8192 + wv * 512]);
        gload_lds16(wg0 + J1 + t * 32, &dst[8192 + (8 + wv) * 512]);
    }
    asm volatile("s_waitcnt vmcnt(8)" ::: "memory");   // tile 0 landed
    __builtin_amdgcn_s_barrier();
    __builtin_amdgcn_sched_barrier(0);

    short8 afA[8], bfA[4], afB[8], bfB[4];
#pragma unroll
    for (int mt = 0; mt < 8; mt++) afA[mt] = *(const short8*)&lds[arow + mt * 512];
#pragma unroll
    for (int nt = 0; nt < 4; nt++) bfA[nt] = *(const short8*)&lds[8192 + brow + nt * 512];

#define GITER(t, afC, bfC, afN, bfN)                                              \
    do {                                                                          \
        const USH* Rd = &lds[(((t) + 1) % 3) * 16384];                            \
        USH* Sd = &lds[((t) % 3) * 16384];                                        \
        if ((t) + 2 < T) asm volatile("s_waitcnt vmcnt(4) lgkmcnt(0)" ::: "memory"); \
        else             asm volatile("s_waitcnt vmcnt(0) lgkmcnt(0)" ::: "memory"); \
        __builtin_amdgcn_s_barrier();                                             \
        __builtin_amdgcn_sched_barrier(0);                                        \
        if ((t) + 3 < T) {                                                        \
            gload_lds16(ag0 + ((t) + 3) * 32,      &Sd[wv * 512]);                \
            gload_lds16(ag0 + J1 + ((t) + 3) * 32, &Sd[(8 + wv) * 512]);          \
            gload_lds16(wg0 + ((t) + 3) * 32,      &Sd[8192 + wv * 512]);         \
            gload_lds16(wg0 + J1 + ((t) + 3) * 32, &Sd[8192 + (8 + wv) * 512]);   \
        }                                                                         \
        if ((t) + 1 < T) {                                                        \
            _Pragma("unroll")                                                     \
            for (int mt_ = 0; mt_ < 8; mt_++)                                     \
                afN[mt_] = *(const short8*)&Rd[arow + mt_ * 512];                 \
            _Pragma("unroll")                                                     \
            for (int nt_ = 0; nt_ < 4; nt_++)                                     \
                bfN[nt_] = *(const short8*)&Rd[8192 + brow + nt_ * 512];          \
        }                                                                         \
        __builtin_amdgcn_s_setprio(1);                                            \
        _Pragma("unroll")                                                         \
        for (int mt_ = 0; mt_ < 8; mt_++)                                         \
            _Pragma("unroll")                                                     \
            for (int nt_ = 0; nt_ < 4; nt_++)                                     \
                acc[mt_][nt_] = mfma16(afC[mt_], bfC[nt_], acc[mt_][nt_]);        \
        __builtin_amdgcn_s_setprio(0);                                            \
    } while (0)

    for (int tt = 0; tt < T; tt += 2) {
        GITER(tt,     afA, bfA, afB, bfB);
        GITER(tt + 1, afB, bfB, afA, bfA);
    }
#undef GITER

    float wm = fmaxf(wsum[0] * (1.f / wcnt), 1e-5f);
#pragma unroll
    for (int mt = 0; mt < 8; mt++)
#pragma unroll
        for (int r = 0; r < 4; r++) {
            int rowg = bm * 256 + wr * 128 + mt * 16 + quad * 4 + r;
            float ia = inva[rowg] * wm;
#pragma unroll
            for (int nt = 0; nt < 4; nt++) {
                int colg = bn * 256 + wc * 64 + nt * 16 + lid;
                float v = acc[mt][nt][r] * ia + bias[colg];
                if (OUT_BF16) ((USH*)out)[(size_t)rowg * Nn + colg] = f2b(v);
                else ((float*)out)[(size_t)rowg * Nn + colg] = v;
            }
        }
}

// ---------------------------------------------------------------------------
// K5: RoPE in place on q,k halves — 4 pairs (16B) per thread. Same per-pair
// fp32 math and f2b rounding as the 1-pair version => bit-identical qkv.
__global__ __launch_bounds__(256) void k_rope(USH* __restrict__ qkv,
                                              const float* __restrict__ cs,
                                              const float* __restrict__ sn) {
    int id = blockIdx.x * 256 + threadIdx.x;    // < 16384*256 (4-pair units)
    int rowm = id >> 8, p4 = id & 255;
    int part = p4 >> 7, pi = p4 & 127;
    int h = pi >> 3, i4 = pi & 7;               // pairs i4*4 .. i4*4+3
    int n = rowm & 8191;
    size_t a = (size_t)rowm * 3072 + part * 1024 + h * 64 + i4 * 8;
    short8 u = *(const short8*)(qkv + a);
    float4 c4 = *(const float4*)&cs[n * 32 + i4 * 4];
    float4 s4 = *(const float4*)&sn[n * 32 + i4 * 4];
    float c[4] = {c4.x, c4.y, c4.z, c4.w};
    float s[4] = {s4.x, s4.y, s4.z, s4.w};
    short8 y;
#pragma unroll
    for (int p = 0; p < 4; p++) {
        float x0 = b2f((USH)u[2 * p]);
        float x1 = b2f((USH)u[2 * p + 1]);
        y[2 * p]     = (short)f2b(x0 * c[p] - x1 * s[p]);
        y[2 * p + 1] = (short)f2b(x1 * c[p] + x0 * s[p]);
    }
    *(short8*)(qkv + a) = y;
}

// ---------------------------------------------------------------------------
// K6 (FUSED intra + kvchunk): per (b,h,t):
//   (1) S = q k^T * scale, causal softmax, O^T = V^T P^T -> oat   (verbatim)
//   (2) KVc[d][e] = sum_seq k[seq][d] v[seq][e]          -> kvc   (verbatim)
// One shared load pass builds qs,kqs (row-major) + kt,vt (transposed).
// LDS: 36864 (qs+kqs, overlaid by P) + 17408 (vt) + 17408 (kt) = 71680 B.
__global__ __launch_bounds__(256) void k_attn_intra(const USH* __restrict__ qkv,
                                                    USH* __restrict__ oat,
                                                    float* __restrict__ kvc) {
    __shared__ char smem[36864 + 17408 + 17408];
    USH* qs = (USH*)smem;                 // [seq][d]  stride 72
    USH* kqs = qs + 128 * 72;             // [seq][d]  stride 72
    USH* Ps = (USH*)smem;                 // overlay: P [seqq][seqk] stride 136
    USH* vt = (USH*)(smem + 36864);       // V^T [e][seq] stride 136
    USH* kt = (USH*)(smem + 36864 + 17408); // K^T [d][seq] stride 136
    int tid = threadIdx.x, wv = tid >> 6, lane = tid & 63, quad = lane >> 4, lid = lane & 15;
    int t = blockIdx.x, bh = blockIdx.y, b = bh >> 4, h = bh & 15;
    size_t base = ((size_t)(b * 8192 + t * 128)) * 3072 + h * 64;
    int r0 = tid >> 3, c0 = (tid & 7) * 8;
#pragma unroll
    for (int i = 0; i < 4; i++) {
        int r = i * 32 + r0;
        short8 qv = *(const short8*)(qkv + base + (size_t)r * 3072 + c0);
        short8 kv = *(const short8*)(qkv + base + (size_t)r * 3072 + 1024 + c0);
        short8 vv = *(const short8*)(qkv + base + (size_t)r * 3072 + 2048 + c0);
        *(short8*)&qs[r * 72 + c0] = qv;
        *(short8*)&kqs[r * 72 + c0] = kv;
        USH tmpv[8]; *(short8*)tmpv = vv;
        USH tmpk[8]; *(short8*)tmpk = kv;
#pragma unroll
        for (int j = 0; j < 8; j++) {
            vt[(c0 + j) * 136 + r] = tmpv[j];
            kt[(c0 + j) * 136 + r] = tmpk[j];
        }
    }
    __syncthreads();

    // ---------------- intra path (verbatim) ----------------
    f32x4 accs[2][8];
#pragma unroll
    for (int mt = 0; mt < 2; mt++)
#pragma unroll
        for (int nt = 0; nt < 8; nt++)
#pragma unroll
            for (int r = 0; r < 4; r++) accs[mt][nt][r] = 0.f;
    int R = wv * 32;
#pragma unroll
    for (int ksx = 0; ksx < 2; ksx++) {
        int co = ksx * 32 + quad * 8;
        short8 af0 = *(const short8*)&qs[(R + lid) * 72 + co];
        short8 af1 = *(const short8*)&qs[(R + 16 + lid) * 72 + co];
        short8 bf[8];
#pragma unroll
        for (int nt = 0; nt < 8; nt++) bf[nt] = *(const short8*)&kqs[(nt * 16 + lid) * 72 + co];
#pragma unroll
        for (int nt = 0; nt < 8; nt++) {
            accs[0][nt] = mfma16(af0, bf[nt], accs[0][nt]);
            accs[1][nt] = mfma16(af1, bf[nt], accs[1][nt]);
        }
    }
    // softmax (rows owned within wave; reduce across 16 lanes of each quad)
#pragma unroll
    for (int mt = 0; mt < 2; mt++)
#pragma unroll
        for (int r = 0; r < 4; r++) {
            int row = R + mt * 16 + quad * 4 + r;
            float sv[8];
            float mx = -3.0e38f;
#pragma unroll
            for (int nt = 0; nt < 8; nt++) {
                int col = nt * 16 + lid;
                float v = accs[mt][nt][r] * 0.125f;
                sv[nt] = (col <= row) ? v : -3.0e38f;
                mx = fmaxf(mx, sv[nt]);
            }
#pragma unroll
            for (int o = 8; o; o >>= 1) mx = fmaxf(mx, __shfl_xor(mx, o));
            float sm = 0.f;
#pragma unroll
            for (int nt = 0; nt < 8; nt++) {
                float e = (sv[nt] > -1.0e38f) ? __expf(sv[nt] - mx) : 0.f;
                sv[nt] = e; sm += e;
            }
#pragma unroll
            for (int o = 8; o; o >>= 1) sm += __shfl_xor(sm, o);
            float inv = 1.f / sm;
#pragma unroll
            for (int nt = 0; nt < 8; nt++) accs[mt][nt][r] = sv[nt] * inv;
        }
    __syncthreads();    // q/k LDS reads done in all waves; safe to overlay P
#pragma unroll
    for (int mt = 0; mt < 2; mt++)
#pragma unroll
        for (int nt = 0; nt < 8; nt++)
#pragma unroll
            for (int r = 0; r < 4; r++)
                Ps[(R + mt * 16 + quad * 4 + r) * 136 + nt * 16 + lid] = f2b(accs[mt][nt][r]);
    __syncthreads();

    // O^T[d][q] = sum_k V^T[d][k] * P[q][k]; wave wv owns d-tile wv
    f32x4 acco[8];
#pragma unroll
    for (int nt = 0; nt < 8; nt++)
#pragma unroll
        for (int r = 0; r < 4; r++) acco[nt][r] = 0.f;
#pragma unroll
    for (int kq = 0; kq < 4; kq++) {
        int co = kq * 32 + quad * 8;
        short8 av = *(const short8*)&vt[(wv * 16 + lid) * 136 + co];
#pragma unroll
        for (int nt = 0; nt < 8; nt++) {
            short8 bp = *(const short8*)&Ps[(nt * 16 + lid) * 136 + co];
            acco[nt] = mfma16(av, bp, acco[nt]);
        }
    }
    size_t obase = (size_t)(b * 8192 + t * 128) * 1024 + h * 64;
#pragma unroll
    for (int nt = 0; nt < 8; nt++)
#pragma unroll
        for (int r = 0; r < 4; r++) {
            int d = wv * 16 + quad * 4 + r;
            int q = nt * 16 + lid;
            oat[obase + (size_t)q * 1024 + d] = f2b(acco[nt][r]);
        }

    // ---------------- kvchunk path (verbatim, reads kt/vt) ----------------
    f32x4 acck[4];
#pragma unroll
    for (int nt = 0; nt < 4; nt++)
#pragma unroll
        for (int r = 0; r < 4; r++) acck[nt][r] = 0.f;
#pragma unroll
    for (int kq = 0; kq < 4; kq++) {
        int co = kq * 32 + quad * 8;
        short8 ak = *(const short8*)&kt[(wv * 16 + lid) * 136 + co];
#pragma unroll
        for (int nt = 0; nt < 4; nt++) {
            short8 bv = *(const short8*)&vt[(nt * 16 + lid) * 136 + co];
            acck[nt] = mfma16(ak, bv, acck[nt]);
        }
    }
    float* outk = kvc + ((size_t)bh * 64 + t) * 4096;
#pragma unroll
    for (int nt = 0; nt < 4; nt++)
#pragma unroll
        for (int r = 0; r < 4; r++) {
            int d = wv * 16 + quad * 4 + r, e = nt * 16 + lid;
            outk[d * 64 + e] = acck[nt][r];
        }
}

// ---------------------------------------------------------------------------
// K7: exclusive prefix over chunk axis of kvc — one chain per thread,
// 131072 independent chains of length 64 (deterministic, coalesced).
__global__ __launch_bounds__(256) void k_prefix(float* __restrict__ kvc) {
    int gid = blockIdx.x * 256 + threadIdx.x;   // 0 .. 131071
    int bh = gid >> 12, idx = gid & 4095;
    float* p = kvc + (size_t)bh * 64 * 4096 + idx;
    float a = 0.f;
    for (int t = 0; t < 64; t++) {
        float c = p[(size_t)t * 4096];
        p[(size_t)t * 4096] = a;
        a += c;
    }
}

// ---------------------------------------------------------------------------
// K8: o_inter[q][e] = sum_d q[q][d] * KVpre[d][e]; RMW-add into out_attn
__global__ __launch_bounds__(256) void k_ointer(const USH* __restrict__ qkv,
                                                const float* __restrict__ kvc,
                                                USH* __restrict__ oat) {
    __shared__ char smem[18432 + 9216];
    USH* qs = (USH*)smem;                  // [seq][d] stride 72
    USH* kvt = (USH*)(smem + 18432);       // KV^T [e][d] stride 72
    int tid = threadIdx.x, wv = tid >> 6, lane = tid & 63, quad = lane >> 4, lid = lane & 15;
    int t = blockIdx.x, bh = blockIdx.y, b = bh >> 4, h = bh & 15;
    size_t base = ((size_t)(b * 8192 + t * 128)) * 3072 + h * 64;
    int r0 = tid >> 3, c0 = (tid & 7) * 8;
#pragma unroll
    for (int i = 0; i < 4; i++) {
        int r = i * 32 + r0;
        short8 qv = *(const short8*)(qkv + base + (size_t)r * 3072 + c0);
        *(short8*)&qs[r * 72 + c0] = qv;
    }
    const float* kv = kvc + ((size_t)bh * 64 + t) * 4096;
#pragma unroll
    for (int j = 0; j < 16; j++) {
        int idx = j * 256 + tid;
        int d = idx >> 6, e = idx & 63;
        kvt[e * 72 + d] = f2b(kv[idx]);
    }
    __syncthreads();
    f32x4 acc[2][4];
#pragma unroll
    for (int mt = 0; mt < 2; mt++)
#pragma unroll
        for (int nt = 0; nt < 4; nt++)
#pragma unroll
            for (int r = 0; r < 4; r++) acc[mt][nt][r] = 0.f;
    int R = wv * 32;
#pragma unroll
    for (int kd = 0; kd < 2; kd++) {
        int co = kd * 32 + quad * 8;
        short8 a0 = *(const short8*)&qs[(R + lid) * 72 + co];
        short8 a1 = *(const short8*)&qs[(R + 16 + lid) * 72 + co];
#pragma unroll
        for (int nt = 0; nt < 4; nt++) {
            short8 bv = *(const short8*)&kvt[(nt * 16 + lid) * 72 + co];
            acc[0][nt] = mfma16(a0, bv, acc[0][nt]);
            acc[1][nt] = mfma16(a1, bv, acc[1][nt]);
        }
    }
#pragma unroll
    for (int mt = 0; mt < 2; mt++)
#pragma unroll
        for (int nt = 0; nt < 4; nt++)
#pragma unroll
            for (int r = 0; r < 4; r++) {
                int row = t * 128 + R + mt * 16 + quad * 4 + r;
                size_t idx = ((size_t)b * 8192 + row) * 1024 + h * 64 + nt * 16 + lid;
                float prev = b2f(oat[idx]);
                oat[idx] = f2b(prev + acc[mt][nt][r]);
            }
}

// ---------------------------------------------------------------------------
extern "C" void kernel_launch(void* const* d_in, const int* in_sizes, int n_in,
                              void* d_out, int out_size, void* d_ws, size_t ws_size,
                              hipStream_t stream) {
    const float* x      = (const float*)d_in[0];
    const float* cosp   = (const float*)d_in[1];
    const float* sinp   = (const float*)d_in[2];
    const float* qkv_w  = (const float*)d_in[3];
    const float* qkv_b  = (const float*)d_in[4];
    const float* qkv_nw = (const float*)d_in[5];
    const float* proj_w = (const float*)d_in[6];
    const float* proj_b = (const float*)d_in[7];
    const float* proj_nw= (const float*)d_in[8];
    const float* norm_w = (const float*)d_in[9];
    float* out = (float*)d_out;

    char* w = (char*)d_ws;
    float* sums    = (float*)(w + 0);                        // 8 B
    float* partials= (float*)(w + 64);                       // 512 f32 = 2048 B
    USH*   wq_qkv  = (USH*)(w + 4096);                       // 6,291,456 B
    USH*   wq_proj = (USH*)(w + 4096 + 6291456);             // 2,097,152 B
    float* inva    = (float*)(w + 8392704);                  // 65,536 B
    char*  R1      = w + 8458240;                            // 33,554,432 B
    char*  R2      = w + 8458240 + 33554432;                 // 33,554,432 B
    USH*   qkv     = (USH*)(w + 8458240 + 2ull * 33554432);  // 100,663,296 B
    USH*   xq      = (USH*)R1;       // stage-1 quantized activations
    USH*   oat     = (USH*)R1;       // out_attn (after xq is dead)
    float* kvc     = (float*)R2;     // chunk KV / exclusive prefix
    USH*   xq2     = (USH*)R2;       // stage-2 quantized activations (after kvc dead)

    k_wabs<<<dim3(256, 2), 256, 0, stream>>>(qkv_w, proj_w, partials);
    k_wsum<<<2, 256, 0, stream>>>(partials, sums);
    k_wquant<<<4096, 256, 0, stream>>>(qkv_w, proj_w, sums, wq_qkv, wq_proj);
    k_actq<<<16384, 256, 0, stream>>>(x, qkv_nw, xq, inva);
    k_gemm<true><<<dim3(12, 64), 512, 0, stream>>>(xq, wq_qkv, inva, &sums[0], 3145728.f,
                                                   qkv_b, (void*)qkv, 3072, 1024);
    k_rope<<<16384, 256, 0, stream>>>(qkv, cosp, sinp);
    k_attn_intra<<<dim3(64, 32), 256, 0, stream>>>(qkv, oat, kvc);
    k_prefix<<<512, 256, 0, stream>>>(kvc);
    k_ointer<<<dim3(64, 32), 256, 0, stream>>>(qkv, kvc, oat);
    k_norm2q<<<16384, 256, 0, stream>>>(oat, norm_w, proj_nw, xq2, inva);
    k_gemm<false><<<dim3(4, 64), 512, 0, stream>>>(xq2, wq_proj, inva, &sums[1], 1048576.f,
                                                   proj_b, (void*)out, 1024, 1024);
    (void)in_sizes; (void)n_in; (void)out_size; (void)ws_size;
}